// Round 15
// baseline (232.410 us; speedup 1.0000x reference)
//
#include <hip/hip_runtime.h>

#define ND 64        // feature dim
#define NR 8         // num edge types
#define NSLICE 8     // dst slices (XCD count)
#define SLICE_NODES 6272   // 196*32; 8*6272 >= 50000
#define TPS 196      // tiles per slice (32 nodes each)
#define NTILE_AL 1568
#define CAPA 216064  // per-slice bucket capacity (mean 200704, ~35 sigma)
#define CAPB 1536    // per-tile bucket capacity (mean 1024, 16 sigma)
#define LPAD 66      // LDS transpose row stride (bank-conflict-free)

typedef __bf16 bf16x8 __attribute__((ext_vector_type(8)));
typedef float f32x4 __attribute__((ext_vector_type(4)));
typedef unsigned short us8 __attribute__((ext_vector_type(8)));

__device__ inline unsigned short bf16_rne(float f) {
    unsigned u = __float_as_uint(f);
    unsigned r = (u + 0x7FFFu + ((u >> 16) & 1u)) >> 16;
    return (unsigned short)r;
}
__device__ inline float bf16_to_f(unsigned short s) {
    return __uint_as_float(((unsigned)s) << 16);
}

// ---------------------------------------------------------------- zero ints
__global__ __launch_bounds__(256) void zeroi_kernel(int* __restrict__ p, int n) {
    int i = blockIdx.x * 256 + threadIdx.x;
    int stride = gridDim.x * 256;
    for (; i < n; i += stride) p[i] = 0;
}

// ---------------------------------------------------------------- A1: bucket edges into 8 dst-slices (proven R10)
__global__ __launch_bounds__(256) void bucket8_kernel(
    const int* __restrict__ src, const int* __restrict__ dst,
    const int* __restrict__ typ, int* __restrict__ bcur,
    uint2* __restrict__ bbufA, int nEdges)
{
    __shared__ uint2 outst[1024];
    __shared__ int lcnt[NSLICE];
    __shared__ int lbase[NSLICE];
    __shared__ int gbase[NSLICE];
    int tid = threadIdx.x;

    for (int base = blockIdx.x * 1024; base < nEdges; base += gridDim.x * 1024) {
        int bn = min(1024, nEdges - base);
        if (tid < NSLICE) lcnt[tid] = 0;
        __syncthreads();
        uint2 ent[4]; int eb[4], eo[4];
#pragma unroll
        for (int k = 0; k < 4; ++k) {
            int i = tid + k * 256;
            eb[k] = -1;
            if (i < bn) {
                int e = base + i;
                int d = dst[e];
                int s = d / SLICE_NODES;
                eb[k] = s;
                ent[k].x = (unsigned)src[e];
                ent[k].y = ((unsigned)s << 16) | ((unsigned)typ[e] << 13) |
                           (unsigned)(d - s * SLICE_NODES);
                eo[k] = atomicAdd(&lcnt[s], 1);
            }
        }
        __syncthreads();
        if (tid == 0) {
            int run = 0;
#pragma unroll
            for (int i = 0; i < NSLICE; ++i) { lbase[i] = run; run += lcnt[i]; }
        }
        if (tid < NSLICE && lcnt[tid] > 0) gbase[tid] = atomicAdd(&bcur[tid], lcnt[tid]);
        __syncthreads();
#pragma unroll
        for (int k = 0; k < 4; ++k)
            if (eb[k] >= 0) outst[lbase[eb[k]] + eo[k]] = ent[k];
        __syncthreads();
#pragma unroll
        for (int k = 0; k < 4; ++k) {
            int i = tid + k * 256;
            if (i < bn) {
                uint2 e = outst[i];
                int s = e.y >> 16;
                bbufA[(long)s * CAPA + gbase[s] + (i - lbase[s])] = e;
            }
        }
        __syncthreads();
    }
}

// ---------------------------------------------------------------- A2: per-slice re-bin into 196 node-tiles (proven R10)
__global__ __launch_bounds__(256) void subbucket_kernel(
    const uint2* __restrict__ bbufA, const int* __restrict__ bcur,
    int* __restrict__ tilecur, uint2* __restrict__ bbufB)
{
    __shared__ uint2 outst[2048];
    __shared__ int lcnt[TPS];
    __shared__ int lbase[TPS];
    __shared__ int gbase[TPS];
    __shared__ int scanbuf[256];
    int tid = threadIdx.x;
    int slice = blockIdx.x & 7;
    int chunk = blockIdx.x >> 3;
    int nchunk = gridDim.x >> 3;
    int n = bcur[slice];
    const uint2* in = bbufA + (long)slice * CAPA;
    int per = (n + nchunk - 1) / nchunk;
    int beg = chunk * per;
    int end = min(beg + per, n);

    for (int b0 = beg; b0 < end; b0 += 2048) {
        int bn = min(2048, end - b0);
        if (tid < TPS) lcnt[tid] = 0;
        __syncthreads();
        uint2 ent[8]; int eb[8], eo[8];
#pragma unroll
        for (int k = 0; k < 8; ++k) {
            int i = tid + k * 256;
            eb[k] = -1;
            if (i < bn) {
                ent[k] = in[b0 + i];
                int bin = (ent[k].y & 8191u) >> 5;
                eb[k] = bin;
                eo[k] = atomicAdd(&lcnt[bin], 1);
            }
        }
        __syncthreads();
        int v = (tid < TPS) ? lcnt[tid] : 0;
        scanbuf[tid] = v;
        __syncthreads();
        int xs = v;
        for (int off = 1; off < 256; off <<= 1) {
            int y = (tid >= off) ? scanbuf[tid - off] : 0;
            __syncthreads();
            xs += y;
            scanbuf[tid] = xs;
            __syncthreads();
        }
        if (tid < TPS) {
            lbase[tid] = xs - v;
            if (v > 0) gbase[tid] = atomicAdd(&tilecur[slice * TPS + tid], v);
        }
        __syncthreads();
#pragma unroll
        for (int k = 0; k < 8; ++k)
            if (eb[k] >= 0) outst[lbase[eb[k]] + eo[k]] = ent[k];
        __syncthreads();
#pragma unroll
        for (int k = 0; k < 8; ++k) {
            int i = tid + k * 256;
            if (i < bn) {
                uint2 e = outst[i];
                int bin = (e.y & 8191u) >> 5;
                bbufB[(long)(slice * TPS + bin) * CAPB + gbase[bin] + (i - lbase[bin])] = e;
            }
        }
        __syncthreads();
    }
}

// ---------------------------------------------------------------- tilescan: prefix over per-tile counts (1 block)
__global__ __launch_bounds__(256) void tilescan_kernel(
    const int* __restrict__ tilecur, int* __restrict__ tilebase,
    int* __restrict__ offsets, int ntAl, int ntUsed, int nEdges)
{
    __shared__ int lds[256];
    int tid = threadIdx.x;
    int v[7]; int lsum = 0;
#pragma unroll
    for (int k = 0; k < 7; ++k) {
        int i = tid * 7 + k;
        v[k] = (i < ntAl) ? tilecur[i] : 0;
        lsum += v[k];
    }
    lds[tid] = lsum;
    __syncthreads();
    int x = lsum;
    for (int off = 1; off < 256; off <<= 1) {
        int y = (tid >= off) ? lds[tid - off] : 0;
        __syncthreads();
        x += y;
        lds[tid] = x;
        __syncthreads();
    }
    int run = x - lsum;
#pragma unroll
    for (int k = 0; k < 7; ++k) {
        int i = tid * 7 + k;
        if (i < ntAl) tilebase[i] = run;
        run += v[k];
    }
    if (tid == 0) offsets[(long)ntUsed * 256] = nEdges;  // sentinel end
}

// ---------------------------------------------------------------- tilesort: per-tile LDS counting sort -> CSR
__global__ __launch_bounds__(256) void tilesort_kernel(
    const uint2* __restrict__ bbufB, const int* __restrict__ tilecur,
    const int* __restrict__ tilebase, int* __restrict__ offsets,
    int* __restrict__ perm)
{
    __shared__ int outst[CAPB];
    __shared__ int lcnt[256];
    __shared__ int sbuf[256];
    __shared__ int cur[256];
    int t = blockIdx.x;
    int tid = threadIdx.x;
    int n = tilecur[t];
    int base = tilebase[t];
    const uint2* buf = bbufB + (long)t * CAPB;

    lcnt[tid] = 0;
    __syncthreads();
    for (int i = tid; i < n; i += 256) {
        uint2 e = buf[i];
        int k = (((e.y >> 13) & 7) << 5) | (e.y & 31);   // r*32 + nl
        atomicAdd(&lcnt[k], 1);
    }
    __syncthreads();
    int v = lcnt[tid];
    sbuf[tid] = v;
    __syncthreads();
    int x = v;
    for (int off = 1; off < 256; off <<= 1) {
        int y = (tid >= off) ? sbuf[tid - off] : 0;
        __syncthreads();
        x += y;
        sbuf[tid] = x;
        __syncthreads();
    }
    int pfx = x - v;
    cur[tid] = pfx;
    offsets[(long)t * 256 + tid] = base + pfx;
    __syncthreads();
    for (int i = tid; i < n; i += 256) {
        uint2 e = buf[i];
        int k = (((e.y >> 13) & 7) << 5) | (e.y & 31);
        int pos = atomicAdd(&cur[k], 1);
        outst[pos] = (int)e.x;
    }
    __syncthreads();
    for (int i = tid; i < n; i += 256) perm[base + i] = outst[i];
}

// ---------------------------------------------------------------- convert_all: wt1|wt2|wm11|wm12|wm21|wm22|xhbf in one launch
__global__ __launch_bounds__(256) void convert_all_kernel(
    const float* __restrict__ W1, const float* __restrict__ W2,
    const float* __restrict__ m1w1, const float* __restrict__ m1w2,
    const float* __restrict__ m2w1, const float* __restrict__ m2w2,
    const float4* __restrict__ x,
    unsigned short* __restrict__ wt1, unsigned short* __restrict__ wt2,
    unsigned short* __restrict__ wm11, unsigned short* __restrict__ wm12,
    unsigned short* __restrict__ wm21, unsigned short* __restrict__ wm22,
    unsigned short* __restrict__ xb, int n8)
{
    int idx = blockIdx.x * 256 + threadIdx.x;
    if (idx < 65536) {                      // wt: [64 o][512 k] = W[k][o]
        const float* W = (idx < 32768) ? W1 : W2;
        unsigned short* wt = (idx < 32768) ? wt1 : wt2;
        int i = idx & 32767;
        int o = i >> 9, k = i & 511;
        wt[i] = bf16_rne(W[(long)k * 64 + o]);
        return;
    }
    idx -= 65536;
    if (idx < 16384) {                      // wm: [64 o][64 k] = m[k][o]
        int which = idx >> 12;
        const float* m = (which == 0) ? m1w1 : (which == 1) ? m1w2
                       : (which == 2) ? m2w1 : m2w2;
        unsigned short* wm = (which == 0) ? wm11 : (which == 1) ? wm12
                           : (which == 2) ? wm21 : wm22;
        int i = idx & 4095;
        int o = i >> 6, k = i & 63;
        wm[i] = bf16_rne(m[k * 64 + o]);
        return;
    }
    idx -= 16384;
    if (idx < n8) {                         // x -> bf16 (8 elems/thread)
        float4 v0 = x[idx * 2], v1 = x[idx * 2 + 1];
        us8 o;
        o[0] = bf16_rne(v0.x); o[1] = bf16_rne(v0.y);
        o[2] = bf16_rne(v0.z); o[3] = bf16_rne(v0.w);
        o[4] = bf16_rne(v1.x); o[5] = bf16_rne(v1.y);
        o[6] = bf16_rne(v1.z); o[7] = bf16_rne(v1.w);
        *(us8*)(xb + (long)idx * 8) = o;
    }
}

// ---------------------------------------------------------------- gather (8-lane groups, ushort8 loads, 4-way interleave)
// Lane owns 8 features (16B load -> 1KB per wave-instr, coalescing sweet spot).
// 8 groups/wave x 4 segments = 32 independent row-chains in flight per wave.
// q-clamp = min(p, e4-1): valid whenever the loop body executes (e4 >= 1).
__global__ __launch_bounds__(256) void gather_kernel(
    const unsigned short* __restrict__ xb, const int* __restrict__ offsets,
    const int* __restrict__ perm, unsigned short* __restrict__ agbf,
    int Stot, int nNodes)
{
    int tid = threadIdx.x;
    int gidx = (blockIdx.x * 256 + tid) >> 3;     // 8 lanes per group
    int nGroups = (gridDim.x * 256) >> 3;
    int fl = tid & 7;                             // lane's 8-feature slice

    for (int s0 = gidx * 4; s0 < Stot; s0 += nGroups * 4) {
        int e0 = offsets[s0];
        int e1 = offsets[s0 + 1];
        int e2 = offsets[s0 + 2];
        int e3 = offsets[s0 + 3];
        int e4 = offsets[s0 + 4];
        int emax = e4 - 1;

        float a0[8], a1[8], a2[8], a3[8];
#pragma unroll
        for (int j = 0; j < 8; ++j) { a0[j] = 0.f; a1[j] = 0.f; a2[j] = 0.f; a3[j] = 0.f; }
        int p0 = e0, p1 = e1, p2 = e2, p3 = e3;

        while ((p0 < e1) | (p1 < e2) | (p2 < e3) | (p3 < e4)) {
            int q0 = min(p0, emax);
            int q1 = min(p1, emax);
            int q2 = min(p2, emax);
            int q3 = min(p3, emax);
            int i0 = perm[q0];
            int i1 = perm[q1];
            int i2 = perm[q2];
            int i3 = perm[q3];
            us8 v0 = *(const us8*)(xb + (long)i0 * ND + fl * 8);
            us8 v1 = *(const us8*)(xb + (long)i1 * ND + fl * 8);
            us8 v2 = *(const us8*)(xb + (long)i2 * ND + fl * 8);
            us8 v3 = *(const us8*)(xb + (long)i3 * ND + fl * 8);
            float m0 = (p0 < e1) ? 1.f : 0.f;
            float m1 = (p1 < e2) ? 1.f : 0.f;
            float m2 = (p2 < e3) ? 1.f : 0.f;
            float m3 = (p3 < e4) ? 1.f : 0.f;
#pragma unroll
            for (int j = 0; j < 8; ++j) {
                a0[j] = fmaf(m0, bf16_to_f(v0[j]), a0[j]);
                a1[j] = fmaf(m1, bf16_to_f(v1[j]), a1[j]);
                a2[j] = fmaf(m2, bf16_to_f(v2[j]), a2[j]);
                a3[j] = fmaf(m3, bf16_to_f(v3[j]), a3[j]);
            }
            p0 += (p0 < e1); p1 += (p1 < e2); p2 += (p2 < e3); p3 += (p3 < e4);
        }

        // write 4 rows: same tile, same r, consecutive nodes (128B per segment)
        int t = s0 >> 8, k0 = s0 & 255;
        int r = k0 >> 5, nl = k0 & 31;
        int node0 = (t << 5) | nl;
        long obase = (long)node0 * 512 + r * ND + fl * 8;
        if (node0 < nNodes) {
            us8 o;
#pragma unroll
            for (int j = 0; j < 8; ++j) o[j] = bf16_rne(a0[j]);
            *(us8*)(agbf + obase) = o;
        }
        if (node0 + 1 < nNodes) {
            us8 o;
#pragma unroll
            for (int j = 0; j < 8; ++j) o[j] = bf16_rne(a1[j]);
            *(us8*)(agbf + obase + 512) = o;
        }
        if (node0 + 2 < nNodes) {
            us8 o;
#pragma unroll
            for (int j = 0; j < 8; ++j) o[j] = bf16_rne(a2[j]);
            *(us8*)(agbf + obase + 1024) = o;
        }
        if (node0 + 3 < nNodes) {
            us8 o;
#pragma unroll
            for (int j = 0; j < 8; ++j) o[j] = bf16_rne(a3[j]);
            *(us8*)(agbf + obase + 1536) = o;
        }
    }
}

// ---------------------------------------------------------------- fused node kernel: einsum + residual + MLP1 + relu + MLP2
__global__ __launch_bounds__(256) void fused_node_kernel(
    const unsigned short* __restrict__ agbf, const unsigned short* __restrict__ wt,
    const float* __restrict__ xin, const float* __restrict__ eps,
    const unsigned short* __restrict__ wm1t, const float* __restrict__ mb1,
    const unsigned short* __restrict__ wm2t, const float* __restrict__ mb2,
    const float* __restrict__ bias,
    float* __restrict__ out, unsigned short* __restrict__ out_bf, int nNodes)
{
    __shared__ float lt_all[4][32 * LPAD];
    int wv = threadIdx.x >> 6;
    int lane = threadIdx.x & 63;
    int wid = blockIdx.x * 4 + wv;
    int nbase = wid * 32;
    if (nbase >= nNodes) return;
    float* lt = lt_all[wv];

    int r16 = lane & 15;
    int kg  = lane >> 4;
    float epsv = 1.0f + eps[0];

    int n0 = nbase + r16;      if (n0 >= nNodes) n0 = nNodes - 1;
    int n1 = nbase + 16 + r16; if (n1 >= nNodes) n1 = nNodes - 1;

    // ---- phase 1: msgs = ag @ Wt^T (K=512)
    f32x4 acc[2][4];
#pragma unroll
    for (int m = 0; m < 2; ++m)
#pragma unroll
        for (int j = 0; j < 4; ++j) acc[m][j] = (f32x4){0.f, 0.f, 0.f, 0.f};
    {
        const unsigned short* a0p = agbf + (long)n0 * 512 + kg * 8;
        const unsigned short* a1p = agbf + (long)n1 * 512 + kg * 8;
        const unsigned short* bp  = wt + (long)r16 * 512 + kg * 8;
#pragma unroll 4
        for (int kk = 0; kk < 16; ++kk) {
            bf16x8 a0 = *(const bf16x8*)(a0p + kk * 32);
            bf16x8 a1 = *(const bf16x8*)(a1p + kk * 32);
#pragma unroll
            for (int j = 0; j < 4; ++j) {
                bf16x8 b = *(const bf16x8*)(bp + (long)j * 16 * 512 + kk * 32);
                acc[0][j] = __builtin_amdgcn_mfma_f32_16x16x32_bf16(a0, b, acc[0][j], 0, 0, 0);
                acc[1][j] = __builtin_amdgcn_mfma_f32_16x16x32_bf16(a1, b, acc[1][j], 0, 0, 0);
            }
        }
    }

    // ---- transpose msgs: C-layout regs -> LDS (row = m*16+kg*4+reg, col = j*16+r16)
#pragma unroll
    for (int m = 0; m < 2; ++m)
#pragma unroll
        for (int reg = 0; reg < 4; ++reg) {
            int row = m * 16 + kg * 4 + reg;
#pragma unroll
            for (int j = 0; j < 4; ++j)
                lt[row * LPAD + j * 16 + r16] = acc[m][j][reg];
        }
    asm volatile("s_waitcnt lgkmcnt(0)" ::: "memory");

    // ---- phase 2: h = (1+eps)*x + msgs; t = relu(h @ wm1t^T + mb1)  (K=64)
    f32x4 acc2[2][4];
#pragma unroll
    for (int m = 0; m < 2; ++m)
#pragma unroll
        for (int j = 0; j < 4; ++j) acc2[m][j] = (f32x4){0.f, 0.f, 0.f, 0.f};
#pragma unroll
    for (int m = 0; m < 2; ++m) {
        int rowl = m * 16 + r16;              // row within wave tile
        long nrow = (m == 0) ? n0 : n1;
#pragma unroll
        for (int kk = 0; kk < 2; ++kk) {
            int k0 = kk * 32 + kg * 8;
            float4 x0 = *(const float4*)(xin + nrow * ND + k0);
            float4 x1 = *(const float4*)(xin + nrow * ND + k0 + 4);
            float4 m0 = *(const float4*)(lt + rowl * LPAD + k0);
            float4 m1 = *(const float4*)(lt + rowl * LPAD + k0 + 4);
            us8 u;
            u[0] = bf16_rne(fmaf(epsv, x0.x, m0.x));
            u[1] = bf16_rne(fmaf(epsv, x0.y, m0.y));
            u[2] = bf16_rne(fmaf(epsv, x0.z, m0.z));
            u[3] = bf16_rne(fmaf(epsv, x0.w, m0.w));
            u[4] = bf16_rne(fmaf(epsv, x1.x, m1.x));
            u[5] = bf16_rne(fmaf(epsv, x1.y, m1.y));
            u[6] = bf16_rne(fmaf(epsv, x1.z, m1.z));
            u[7] = bf16_rne(fmaf(epsv, x1.w, m1.w));
            bf16x8 a = __builtin_bit_cast(bf16x8, u);
#pragma unroll
            for (int j = 0; j < 4; ++j) {
                bf16x8 b = *(const bf16x8*)(wm1t + (long)(j * 16 + r16) * ND + k0);
                acc2[m][j] = __builtin_amdgcn_mfma_f32_16x16x32_bf16(a, b, acc2[m][j], 0, 0, 0);
            }
        }
    }

    // ---- transpose t (with bias+relu): regs -> LDS
    asm volatile("s_waitcnt lgkmcnt(0)" ::: "memory");  // drain phase-2 reads before overwrite
#pragma unroll
    for (int m = 0; m < 2; ++m)
#pragma unroll
        for (int reg = 0; reg < 4; ++reg) {
            int row = m * 16 + kg * 4 + reg;
#pragma unroll
            for (int j = 0; j < 4; ++j) {
                int col = j * 16 + r16;
                lt[row * LPAD + col] = fmaxf(acc2[m][j][reg] + mb1[col], 0.f);
            }
        }
    asm volatile("s_waitcnt lgkmcnt(0)" ::: "memory");

    // ---- phase 3: out = t @ wm2t^T + mb2 + bias  (K=64)
    f32x4 acc3[2][4];
#pragma unroll
    for (int m = 0; m < 2; ++m)
#pragma unroll
        for (int j = 0; j < 4; ++j) acc3[m][j] = (f32x4){0.f, 0.f, 0.f, 0.f};
#pragma unroll
    for (int m = 0; m < 2; ++m) {
        int rowl = m * 16 + r16;
#pragma unroll
        for (int kk = 0; kk < 2; ++kk) {
            int k0 = kk * 32 + kg * 8;
            float4 t0 = *(const float4*)(lt + rowl * LPAD + k0);
            float4 t1 = *(const float4*)(lt + rowl * LPAD + k0 + 4);
            us8 u;
            u[0] = bf16_rne(t0.x); u[1] = bf16_rne(t0.y);
            u[2] = bf16_rne(t0.z); u[3] = bf16_rne(t0.w);
            u[4] = bf16_rne(t1.x); u[5] = bf16_rne(t1.y);
            u[6] = bf16_rne(t1.z); u[7] = bf16_rne(t1.w);
            bf16x8 a = __builtin_bit_cast(bf16x8, u);
#pragma unroll
            for (int j = 0; j < 4; ++j) {
                bf16x8 b = *(const bf16x8*)(wm2t + (long)(j * 16 + r16) * ND + k0);
                acc3[m][j] = __builtin_amdgcn_mfma_f32_16x16x32_bf16(a, b, acc3[m][j], 0, 0, 0);
            }
        }
    }

    // ---- epilogue: out (f32) + optional bf16 copy
#pragma unroll
    for (int m = 0; m < 2; ++m) {
#pragma unroll
        for (int reg = 0; reg < 4; ++reg) {
            int row = nbase + m * 16 + kg * 4 + reg;
            if (row < nNodes) {
#pragma unroll
                for (int j = 0; j < 4; ++j) {
                    int col = j * 16 + r16;
                    float v = acc3[m][j][reg] + mb2[col] + bias[col];
                    out[(long)row * ND + col] = v;
                    if (out_bf != nullptr)
                        out_bf[(long)row * ND + col] = bf16_rne(v);
                }
            }
        }
    }
}

// ---------------------------------------------------------------- launch
extern "C" void kernel_launch(void* const* d_in, const int* in_sizes, int n_in,
                              void* d_out, int out_size, void* d_ws, size_t ws_size,
                              hipStream_t stream) {
    const float* x    = (const float*)d_in[0];
    const int* esrc   = (const int*)d_in[1];
    const int* edst   = (const int*)d_in[2];
    const int* etyp   = (const int*)d_in[3];

    const float* W1   = (const float*)d_in[4];
    const float* b1   = (const float*)d_in[5];
    const float* e1   = (const float*)d_in[6];
    const float* m1w1 = (const float*)d_in[7];
    const float* m1b1 = (const float*)d_in[8];
    const float* m1w2 = (const float*)d_in[9];
    const float* m1b2 = (const float*)d_in[10];

    const float* W2   = (const float*)d_in[11];
    const float* b2   = (const float*)d_in[12];
    const float* e2   = (const float*)d_in[13];
    const float* m2w1 = (const float*)d_in[14];
    const float* m2b1 = (const float*)d_in[15];
    const float* m2w2 = (const float*)d_in[16];
    const float* m2b2 = (const float*)d_in[17];

    int nNodes = in_sizes[0] / ND;   // 50000
    int nEdges = in_sizes[1];        // 1600000
    int ntiles = (nNodes + 31) / 32; // 1563
    int Stot = ntiles * 256;         // 400128 segments (incl. padding nodes)

    // ---- workspace layout (~112 MB)
    unsigned short* agbf = (unsigned short*)d_ws;                 // N*512 bf16 = 51.2MB
    unsigned short* xhbf = agbf + (long)nNodes * 512;             // N*64 bf16 = 6.4MB
    unsigned short* wt1  = xhbf + (long)nNodes * ND;
    unsigned short* wt2  = wt1 + 64 * 512;
    unsigned short* wm11 = wt2 + 64 * 512;
    unsigned short* wm12 = wm11 + 64 * 64;
    unsigned short* wm21 = wm12 + 64 * 64;
    unsigned short* wm22 = wm21 + 64 * 64;
    uint2* bbufA  = (uint2*)(wm22 + 64 * 64);                     // 13.8MB
    uint2* bbufB  = bbufA + (long)NSLICE * CAPA;                  // 19.3MB
    int* cnts     = (int*)(bbufB + (long)NTILE_AL * CAPB);
    int* bcur     = cnts;                                         // 8
    int* tilecur  = cnts + NSLICE;                                // 1568
    int* tilebase = tilecur + NTILE_AL;                           // 1568
    int* offsets  = tilebase + NTILE_AL;                          // Stot+1
    int* perm     = offsets + (Stot + 256);                       // E ints = 6.4MB
    float* h    = (float*)d_out;   // layer-1 fp32 h aliases d_out
    float* outp = (float*)d_out;

    int fgrid = (ntiles + 3) / 4;    // 4 waves/block, 32 nodes/wave
    int n8 = nNodes * ND / 8;
    int cvtotal = 65536 + 16384 + n8;

    // ---- build per-segment CSR via LDS-staged two-level bucketing (all dense writes)
    zeroi_kernel<<<7, 256, 0, stream>>>(cnts, NSLICE + NTILE_AL);
    bucket8_kernel<<<782, 256, 0, stream>>>(esrc, edst, etyp, bcur, bbufA, nEdges);
    subbucket_kernel<<<320, 256, 0, stream>>>(bbufA, bcur, tilecur, bbufB);
    tilescan_kernel<<<1, 256, 0, stream>>>(tilecur, tilebase, offsets, NTILE_AL, ntiles, nEdges);
    tilesort_kernel<<<ntiles, 256, 0, stream>>>(bbufB, tilecur, tilebase, offsets, perm);

    // ---- all weight/x converts in one launch
    convert_all_kernel<<<(cvtotal + 255) / 256, 256, 0, stream>>>(
        W1, W2, m1w1, m1w2, m2w1, m2w2, (const float4*)x,
        wt1, wt2, wm11, wm12, wm21, wm22, xhbf, n8);

    // ---- layer 1
    gather_kernel<<<2048, 256, 0, stream>>>(xhbf, offsets, perm, agbf, Stot, nNodes);
    fused_node_kernel<<<fgrid, 256, 0, stream>>>(agbf, wt1, x, e1, wm11, m1b1,
                                                 wm12, m1b2, b1, h, xhbf, nNodes);

    // ---- layer 2
    gather_kernel<<<2048, 256, 0, stream>>>(xhbf, offsets, perm, agbf, Stot, nNodes);
    fused_node_kernel<<<fgrid, 256, 0, stream>>>(agbf, wt2, h, e2, wm21, m2b1,
                                                 wm22, m2b2, b2, outp, nullptr, nNodes);
}

// Round 16
// 224.095 us; speedup vs baseline: 1.0371x; 1.0371x over previous
//
#include <hip/hip_runtime.h>

#define ND 64        // feature dim
#define NR 8         // num edge types
#define NSLICE 8     // dst slices (XCD count)
#define SLICE_NODES 6272   // 196*32; 8*6272 >= 50000
#define TPS 196      // tiles per slice (32 nodes each)
#define NTILE_AL 1568
#define CAPA 216064  // per-slice bucket capacity (mean 200704, ~35 sigma)
#define CAPB 1536    // per-tile bucket capacity (mean 1024, 16 sigma)
#define LPAD 66      // LDS transpose row stride (bank-conflict-free)

typedef __bf16 bf16x8 __attribute__((ext_vector_type(8)));
typedef float f32x4 __attribute__((ext_vector_type(4)));
typedef unsigned short us8 __attribute__((ext_vector_type(8)));

__device__ inline unsigned short bf16_rne(float f) {
    unsigned u = __float_as_uint(f);
    unsigned r = (u + 0x7FFFu + ((u >> 16) & 1u)) >> 16;
    return (unsigned short)r;
}
__device__ inline float bf16_to_f(unsigned short s) {
    return __uint_as_float(((unsigned)s) << 16);
}

// ---------------------------------------------------------------- zero ints
__global__ __launch_bounds__(256) void zeroi_kernel(int* __restrict__ p, int n) {
    int i = blockIdx.x * 256 + threadIdx.x;
    int stride = gridDim.x * 256;
    for (; i < n; i += stride) p[i] = 0;
}

// ---------------------------------------------------------------- A1: bucket edges into 8 dst-slices (proven R10)
__global__ __launch_bounds__(256) void bucket8_kernel(
    const int* __restrict__ src, const int* __restrict__ dst,
    const int* __restrict__ typ, int* __restrict__ bcur,
    uint2* __restrict__ bbufA, int nEdges)
{
    __shared__ uint2 outst[1024];
    __shared__ int lcnt[NSLICE];
    __shared__ int lbase[NSLICE];
    __shared__ int gbase[NSLICE];
    int tid = threadIdx.x;

    for (int base = blockIdx.x * 1024; base < nEdges; base += gridDim.x * 1024) {
        int bn = min(1024, nEdges - base);
        if (tid < NSLICE) lcnt[tid] = 0;
        __syncthreads();
        uint2 ent[4]; int eb[4], eo[4];
#pragma unroll
        for (int k = 0; k < 4; ++k) {
            int i = tid + k * 256;
            eb[k] = -1;
            if (i < bn) {
                int e = base + i;
                int d = dst[e];
                int s = d / SLICE_NODES;
                eb[k] = s;
                ent[k].x = (unsigned)src[e];
                ent[k].y = ((unsigned)s << 16) | ((unsigned)typ[e] << 13) |
                           (unsigned)(d - s * SLICE_NODES);
                eo[k] = atomicAdd(&lcnt[s], 1);
            }
        }
        __syncthreads();
        if (tid == 0) {
            int run = 0;
#pragma unroll
            for (int i = 0; i < NSLICE; ++i) { lbase[i] = run; run += lcnt[i]; }
        }
        if (tid < NSLICE && lcnt[tid] > 0) gbase[tid] = atomicAdd(&bcur[tid], lcnt[tid]);
        __syncthreads();
#pragma unroll
        for (int k = 0; k < 4; ++k)
            if (eb[k] >= 0) outst[lbase[eb[k]] + eo[k]] = ent[k];
        __syncthreads();
#pragma unroll
        for (int k = 0; k < 4; ++k) {
            int i = tid + k * 256;
            if (i < bn) {
                uint2 e = outst[i];
                int s = e.y >> 16;
                bbufA[(long)s * CAPA + gbase[s] + (i - lbase[s])] = e;
            }
        }
        __syncthreads();
    }
}

// ---------------------------------------------------------------- A2: per-slice re-bin into 196 node-tiles (proven R10)
__global__ __launch_bounds__(256) void subbucket_kernel(
    const uint2* __restrict__ bbufA, const int* __restrict__ bcur,
    int* __restrict__ tilecur, uint2* __restrict__ bbufB)
{
    __shared__ uint2 outst[2048];
    __shared__ int lcnt[TPS];
    __shared__ int lbase[TPS];
    __shared__ int gbase[TPS];
    __shared__ int scanbuf[256];
    int tid = threadIdx.x;
    int slice = blockIdx.x & 7;
    int chunk = blockIdx.x >> 3;
    int nchunk = gridDim.x >> 3;
    int n = bcur[slice];
    const uint2* in = bbufA + (long)slice * CAPA;
    int per = (n + nchunk - 1) / nchunk;
    int beg = chunk * per;
    int end = min(beg + per, n);

    for (int b0 = beg; b0 < end; b0 += 2048) {
        int bn = min(2048, end - b0);
        if (tid < TPS) lcnt[tid] = 0;
        __syncthreads();
        uint2 ent[8]; int eb[8], eo[8];
#pragma unroll
        for (int k = 0; k < 8; ++k) {
            int i = tid + k * 256;
            eb[k] = -1;
            if (i < bn) {
                ent[k] = in[b0 + i];
                int bin = (ent[k].y & 8191u) >> 5;
                eb[k] = bin;
                eo[k] = atomicAdd(&lcnt[bin], 1);
            }
        }
        __syncthreads();
        int v = (tid < TPS) ? lcnt[tid] : 0;
        scanbuf[tid] = v;
        __syncthreads();
        int xs = v;
        for (int off = 1; off < 256; off <<= 1) {
            int y = (tid >= off) ? scanbuf[tid - off] : 0;
            __syncthreads();
            xs += y;
            scanbuf[tid] = xs;
            __syncthreads();
        }
        if (tid < TPS) {
            lbase[tid] = xs - v;
            if (v > 0) gbase[tid] = atomicAdd(&tilecur[slice * TPS + tid], v);
        }
        __syncthreads();
#pragma unroll
        for (int k = 0; k < 8; ++k)
            if (eb[k] >= 0) outst[lbase[eb[k]] + eo[k]] = ent[k];
        __syncthreads();
#pragma unroll
        for (int k = 0; k < 8; ++k) {
            int i = tid + k * 256;
            if (i < bn) {
                uint2 e = outst[i];
                int bin = (e.y & 8191u) >> 5;
                bbufB[(long)(slice * TPS + bin) * CAPB + gbase[bin] + (i - lbase[bin])] = e;
            }
        }
        __syncthreads();
    }
}

// ---------------------------------------------------------------- tilescan: prefix over per-tile counts (1 block)
__global__ __launch_bounds__(256) void tilescan_kernel(
    const int* __restrict__ tilecur, int* __restrict__ tilebase,
    int* __restrict__ offsets, int ntAl, int ntUsed, int nEdges)
{
    __shared__ int lds[256];
    int tid = threadIdx.x;
    int v[7]; int lsum = 0;
#pragma unroll
    for (int k = 0; k < 7; ++k) {
        int i = tid * 7 + k;
        v[k] = (i < ntAl) ? tilecur[i] : 0;
        lsum += v[k];
    }
    lds[tid] = lsum;
    __syncthreads();
    int x = lsum;
    for (int off = 1; off < 256; off <<= 1) {
        int y = (tid >= off) ? lds[tid - off] : 0;
        __syncthreads();
        x += y;
        lds[tid] = x;
        __syncthreads();
    }
    int run = x - lsum;
#pragma unroll
    for (int k = 0; k < 7; ++k) {
        int i = tid * 7 + k;
        if (i < ntAl) tilebase[i] = run;
        run += v[k];
    }
    if (tid == 0) offsets[(long)ntUsed * 256] = nEdges;  // sentinel end
}

// ---------------------------------------------------------------- tilesort: per-tile LDS counting sort -> CSR
// + length-sorted segment order (quadlist) for balanced gather quads.
__global__ __launch_bounds__(256) void tilesort_kernel(
    const uint2* __restrict__ bbufB, const int* __restrict__ tilecur,
    const int* __restrict__ tilebase, int* __restrict__ offsets,
    int* __restrict__ perm, unsigned char* __restrict__ quadlist)
{
    __shared__ int outst[CAPB];
    __shared__ int lcnt[256];
    __shared__ int sbuf[256];
    __shared__ int cur[256];
    __shared__ int hist2[32];
    __shared__ int hcur2[32];
    __shared__ unsigned char qorder[256];
    int t = blockIdx.x;
    int tid = threadIdx.x;
    int n = tilecur[t];
    int base = tilebase[t];
    const uint2* buf = bbufB + (long)t * CAPB;

    lcnt[tid] = 0;
    __syncthreads();
    for (int i = tid; i < n; i += 256) {
        uint2 e = buf[i];
        int k = (((e.y >> 13) & 7) << 5) | (e.y & 31);   // r*32 + nl
        atomicAdd(&lcnt[k], 1);
    }
    __syncthreads();
    int v = lcnt[tid];
    sbuf[tid] = v;
    __syncthreads();
    int x = v;
    for (int off = 1; off < 256; off <<= 1) {
        int y = (tid >= off) ? sbuf[tid - off] : 0;
        __syncthreads();
        x += y;
        sbuf[tid] = x;
        __syncthreads();
    }
    int pfx = x - v;
    cur[tid] = pfx;
    offsets[(long)t * 256 + tid] = base + pfx;
    __syncthreads();
    for (int i = tid; i < n; i += 256) {
        uint2 e = buf[i];
        int k = (((e.y >> 13) & 7) << 5) | (e.y & 31);
        int pos = atomicAdd(&cur[k], 1);
        outst[pos] = (int)e.x;
    }
    __syncthreads();
    for (int i = tid; i < n; i += 256) perm[base + i] = outst[i];

    // ---- length-sorted segment order (32-bin counting sort; empty segs first)
    int len2 = min(v, 31);
    if (tid < 32) hist2[tid] = 0;
    __syncthreads();
    atomicAdd(&hist2[len2], 1);
    __syncthreads();
    if (tid == 0) {
        int run = 0;
#pragma unroll
        for (int i = 0; i < 32; ++i) { hcur2[i] = run; run += hist2[i]; }
    }
    __syncthreads();
    int sp = atomicAdd(&hcur2[len2], 1);
    qorder[sp] = (unsigned char)tid;
    __syncthreads();
    quadlist[((long)t << 8) + tid] = qorder[tid];
}

// ---------------------------------------------------------------- convert_all: wt1|wt2|wm11|wm12|wm21|wm22|xhbf in one launch
__global__ __launch_bounds__(256) void convert_all_kernel(
    const float* __restrict__ W1, const float* __restrict__ W2,
    const float* __restrict__ m1w1, const float* __restrict__ m1w2,
    const float* __restrict__ m2w1, const float* __restrict__ m2w2,
    const float4* __restrict__ x,
    unsigned short* __restrict__ wt1, unsigned short* __restrict__ wt2,
    unsigned short* __restrict__ wm11, unsigned short* __restrict__ wm12,
    unsigned short* __restrict__ wm21, unsigned short* __restrict__ wm22,
    unsigned short* __restrict__ xb, int n8)
{
    int idx = blockIdx.x * 256 + threadIdx.x;
    if (idx < 65536) {                      // wt: [64 o][512 k] = W[k][o]
        const float* W = (idx < 32768) ? W1 : W2;
        unsigned short* wt = (idx < 32768) ? wt1 : wt2;
        int i = idx & 32767;
        int o = i >> 9, k = i & 511;
        wt[i] = bf16_rne(W[(long)k * 64 + o]);
        return;
    }
    idx -= 65536;
    if (idx < 16384) {                      // wm: [64 o][64 k] = m[k][o]
        int which = idx >> 12;
        const float* m = (which == 0) ? m1w1 : (which == 1) ? m1w2
                       : (which == 2) ? m2w1 : m2w2;
        unsigned short* wm = (which == 0) ? wm11 : (which == 1) ? wm12
                           : (which == 2) ? wm21 : wm22;
        int i = idx & 4095;
        int o = i >> 6, k = i & 63;
        wm[i] = bf16_rne(m[k * 64 + o]);
        return;
    }
    idx -= 16384;
    if (idx < n8) {                         // x -> bf16 (8 elems/thread)
        float4 v0 = x[idx * 2], v1 = x[idx * 2 + 1];
        us8 o;
        o[0] = bf16_rne(v0.x); o[1] = bf16_rne(v0.y);
        o[2] = bf16_rne(v0.z); o[3] = bf16_rne(v0.w);
        o[4] = bf16_rne(v1.x); o[5] = bf16_rne(v1.y);
        o[6] = bf16_rne(v1.z); o[7] = bf16_rne(v1.w);
        *(us8*)(xb + (long)idx * 8) = o;
    }
}

// ---------------------------------------------------------------- gather (length-balanced quads via quadlist)
// Quad q = 4 segments of near-equal length from tile q>>6 (length-sorted in
// tilesort) -> loop runs ~mean(len) not max(len). Each segment writes its own
// ALIGNED 128B block (scattered >=64B stores carry no write-amp penalty).
__global__ __launch_bounds__(256) void gather_kernel(
    const unsigned short* __restrict__ xb, const int* __restrict__ offsets,
    const int* __restrict__ perm, const unsigned char* __restrict__ quadlist,
    unsigned short* __restrict__ agbf, int nQuads, int nNodes, int permMax)
{
    int tid = threadIdx.x;
    int gidx = (blockIdx.x * 256 + tid) >> 3;     // 8 lanes per group
    int nGroups = (gridDim.x * 256) >> 3;
    int fl = tid & 7;                             // lane's 8-feature slice

    for (int q = gidx; q < nQuads; q += nGroups) {
        int t = q >> 6;
        int ql = q & 63;
        uchar4 s4 = *(const uchar4*)(quadlist + ((long)t << 8) + (ql << 2));
        int sb = t << 8;
        int sid0 = s4.x, sid1 = s4.y, sid2 = s4.z, sid3 = s4.w;
        int b0 = offsets[sb + sid0], E0 = offsets[sb + sid0 + 1];
        int b1 = offsets[sb + sid1], E1 = offsets[sb + sid1 + 1];
        int b2 = offsets[sb + sid2], E2 = offsets[sb + sid2 + 1];
        int b3 = offsets[sb + sid3], E3 = offsets[sb + sid3 + 1];

        float a0[8], a1[8], a2[8], a3[8];
#pragma unroll
        for (int j = 0; j < 8; ++j) { a0[j] = 0.f; a1[j] = 0.f; a2[j] = 0.f; a3[j] = 0.f; }
        int p0 = b0, p1 = b1, p2 = b2, p3 = b3;

        while ((p0 < E0) | (p1 < E1) | (p2 < E2) | (p3 < E3)) {
            int q0 = min(p0, permMax);
            int q1 = min(p1, permMax);
            int q2 = min(p2, permMax);
            int q3 = min(p3, permMax);
            int i0 = perm[q0];
            int i1 = perm[q1];
            int i2 = perm[q2];
            int i3 = perm[q3];
            us8 v0 = *(const us8*)(xb + (long)i0 * ND + fl * 8);
            us8 v1 = *(const us8*)(xb + (long)i1 * ND + fl * 8);
            us8 v2 = *(const us8*)(xb + (long)i2 * ND + fl * 8);
            us8 v3 = *(const us8*)(xb + (long)i3 * ND + fl * 8);
            float m0 = (p0 < E0) ? 1.f : 0.f;
            float m1 = (p1 < E1) ? 1.f : 0.f;
            float m2 = (p2 < E2) ? 1.f : 0.f;
            float m3 = (p3 < E3) ? 1.f : 0.f;
#pragma unroll
            for (int j = 0; j < 8; ++j) {
                a0[j] = fmaf(m0, bf16_to_f(v0[j]), a0[j]);
                a1[j] = fmaf(m1, bf16_to_f(v1[j]), a1[j]);
                a2[j] = fmaf(m2, bf16_to_f(v2[j]), a2[j]);
                a3[j] = fmaf(m3, bf16_to_f(v3[j]), a3[j]);
            }
            p0 += (p0 < E0); p1 += (p1 < E1); p2 += (p2 < E2); p3 += (p3 < E3);
        }

        // each segment writes its own aligned 128B slice
        int nb = t << 5;
#define WR(sid, a)                                                          \
        {                                                                   \
            int node = nb | (sid & 31);                                     \
            if (node < nNodes) {                                            \
                us8 o;                                                      \
                _Pragma("unroll")                                           \
                for (int j = 0; j < 8; ++j) o[j] = bf16_rne(a[j]);          \
                *(us8*)(agbf + (long)node * 512 + (sid >> 5) * ND + fl * 8) = o; \
            }                                                               \
        }
        WR(sid0, a0) WR(sid1, a1) WR(sid2, a2) WR(sid3, a3)
#undef WR
    }
}

// ---------------------------------------------------------------- fused node kernel: einsum + residual + MLP1 + relu + MLP2
__global__ __launch_bounds__(256) void fused_node_kernel(
    const unsigned short* __restrict__ agbf, const unsigned short* __restrict__ wt,
    const float* __restrict__ xin, const float* __restrict__ eps,
    const unsigned short* __restrict__ wm1t, const float* __restrict__ mb1,
    const unsigned short* __restrict__ wm2t, const float* __restrict__ mb2,
    const float* __restrict__ bias,
    float* __restrict__ out, unsigned short* __restrict__ out_bf, int nNodes)
{
    __shared__ float lt_all[4][32 * LPAD];
    int wv = threadIdx.x >> 6;
    int lane = threadIdx.x & 63;
    int wid = blockIdx.x * 4 + wv;
    int nbase = wid * 32;
    if (nbase >= nNodes) return;
    float* lt = lt_all[wv];

    int r16 = lane & 15;
    int kg  = lane >> 4;
    float epsv = 1.0f + eps[0];

    int n0 = nbase + r16;      if (n0 >= nNodes) n0 = nNodes - 1;
    int n1 = nbase + 16 + r16; if (n1 >= nNodes) n1 = nNodes - 1;

    // ---- phase 1: msgs = ag @ Wt^T (K=512)
    f32x4 acc[2][4];
#pragma unroll
    for (int m = 0; m < 2; ++m)
#pragma unroll
        for (int j = 0; j < 4; ++j) acc[m][j] = (f32x4){0.f, 0.f, 0.f, 0.f};
    {
        const unsigned short* a0p = agbf + (long)n0 * 512 + kg * 8;
        const unsigned short* a1p = agbf + (long)n1 * 512 + kg * 8;
        const unsigned short* bp  = wt + (long)r16 * 512 + kg * 8;
#pragma unroll 4
        for (int kk = 0; kk < 16; ++kk) {
            bf16x8 a0 = *(const bf16x8*)(a0p + kk * 32);
            bf16x8 a1 = *(const bf16x8*)(a1p + kk * 32);
#pragma unroll
            for (int j = 0; j < 4; ++j) {
                bf16x8 b = *(const bf16x8*)(bp + (long)j * 16 * 512 + kk * 32);
                acc[0][j] = __builtin_amdgcn_mfma_f32_16x16x32_bf16(a0, b, acc[0][j], 0, 0, 0);
                acc[1][j] = __builtin_amdgcn_mfma_f32_16x16x32_bf16(a1, b, acc[1][j], 0, 0, 0);
            }
        }
    }

    // ---- transpose msgs: C-layout regs -> LDS (row = m*16+kg*4+reg, col = j*16+r16)
#pragma unroll
    for (int m = 0; m < 2; ++m)
#pragma unroll
        for (int reg = 0; reg < 4; ++reg) {
            int row = m * 16 + kg * 4 + reg;
#pragma unroll
            for (int j = 0; j < 4; ++j)
                lt[row * LPAD + j * 16 + r16] = acc[m][j][reg];
        }
    asm volatile("s_waitcnt lgkmcnt(0)" ::: "memory");

    // ---- phase 2: h = (1+eps)*x + msgs; t = relu(h @ wm1t^T + mb1)  (K=64)
    f32x4 acc2[2][4];
#pragma unroll
    for (int m = 0; m < 2; ++m)
#pragma unroll
        for (int j = 0; j < 4; ++j) acc2[m][j] = (f32x4){0.f, 0.f, 0.f, 0.f};
#pragma unroll
    for (int m = 0; m < 2; ++m) {
        int rowl = m * 16 + r16;              // row within wave tile
        long nrow = (m == 0) ? n0 : n1;
#pragma unroll
        for (int kk = 0; kk < 2; ++kk) {
            int k0 = kk * 32 + kg * 8;
            float4 x0 = *(const float4*)(xin + nrow * ND + k0);
            float4 x1 = *(const float4*)(xin + nrow * ND + k0 + 4);
            float4 m0 = *(const float4*)(lt + rowl * LPAD + k0);
            float4 m1 = *(const float4*)(lt + rowl * LPAD + k0 + 4);
            us8 u;
            u[0] = bf16_rne(fmaf(epsv, x0.x, m0.x));
            u[1] = bf16_rne(fmaf(epsv, x0.y, m0.y));
            u[2] = bf16_rne(fmaf(epsv, x0.z, m0.z));
            u[3] = bf16_rne(fmaf(epsv, x0.w, m0.w));
            u[4] = bf16_rne(fmaf(epsv, x1.x, m1.x));
            u[5] = bf16_rne(fmaf(epsv, x1.y, m1.y));
            u[6] = bf16_rne(fmaf(epsv, x1.z, m1.z));
            u[7] = bf16_rne(fmaf(epsv, x1.w, m1.w));
            bf16x8 a = __builtin_bit_cast(bf16x8, u);
#pragma unroll
            for (int j = 0; j < 4; ++j) {
                bf16x8 b = *(const bf16x8*)(wm1t + (long)(j * 16 + r16) * ND + k0);
                acc2[m][j] = __builtin_amdgcn_mfma_f32_16x16x32_bf16(a, b, acc2[m][j], 0, 0, 0);
            }
        }
    }

    // ---- transpose t (with bias+relu): regs -> LDS
    asm volatile("s_waitcnt lgkmcnt(0)" ::: "memory");  // drain phase-2 reads before overwrite
#pragma unroll
    for (int m = 0; m < 2; ++m)
#pragma unroll
        for (int reg = 0; reg < 4; ++reg) {
            int row = m * 16 + kg * 4 + reg;
#pragma unroll
            for (int j = 0; j < 4; ++j) {
                int col = j * 16 + r16;
                lt[row * LPAD + col] = fmaxf(acc2[m][j][reg] + mb1[col], 0.f);
            }
        }
    asm volatile("s_waitcnt lgkmcnt(0)" ::: "memory");

    // ---- phase 3: out = t @ wm2t^T + mb2 + bias  (K=64)
    f32x4 acc3[2][4];
#pragma unroll
    for (int m = 0; m < 2; ++m)
#pragma unroll
        for (int j = 0; j < 4; ++j) acc3[m][j] = (f32x4){0.f, 0.f, 0.f, 0.f};
#pragma unroll
    for (int m = 0; m < 2; ++m) {
        int rowl = m * 16 + r16;
#pragma unroll
        for (int kk = 0; kk < 2; ++kk) {
            int k0 = kk * 32 + kg * 8;
            float4 t0 = *(const float4*)(lt + rowl * LPAD + k0);
            float4 t1 = *(const float4*)(lt + rowl * LPAD + k0 + 4);
            us8 u;
            u[0] = bf16_rne(t0.x); u[1] = bf16_rne(t0.y);
            u[2] = bf16_rne(t0.z); u[3] = bf16_rne(t0.w);
            u[4] = bf16_rne(t1.x); u[5] = bf16_rne(t1.y);
            u[6] = bf16_rne(t1.z); u[7] = bf16_rne(t1.w);
            bf16x8 a = __builtin_bit_cast(bf16x8, u);
#pragma unroll
            for (int j = 0; j < 4; ++j) {
                bf16x8 b = *(const bf16x8*)(wm2t + (long)(j * 16 + r16) * ND + k0);
                acc3[m][j] = __builtin_amdgcn_mfma_f32_16x16x32_bf16(a, b, acc3[m][j], 0, 0, 0);
            }
        }
    }

    // ---- epilogue: out (f32) + optional bf16 copy
#pragma unroll
    for (int m = 0; m < 2; ++m) {
#pragma unroll
        for (int reg = 0; reg < 4; ++reg) {
            int row = nbase + m * 16 + kg * 4 + reg;
            if (row < nNodes) {
#pragma unroll
                for (int j = 0; j < 4; ++j) {
                    int col = j * 16 + r16;
                    float v = acc3[m][j][reg] + mb2[col] + bias[col];
                    out[(long)row * ND + col] = v;
                    if (out_bf != nullptr)
                        out_bf[(long)row * ND + col] = bf16_rne(v);
                }
            }
        }
    }
}

// ---------------------------------------------------------------- launch
extern "C" void kernel_launch(void* const* d_in, const int* in_sizes, int n_in,
                              void* d_out, int out_size, void* d_ws, size_t ws_size,
                              hipStream_t stream) {
    const float* x    = (const float*)d_in[0];
    const int* esrc   = (const int*)d_in[1];
    const int* edst   = (const int*)d_in[2];
    const int* etyp   = (const int*)d_in[3];

    const float* W1   = (const float*)d_in[4];
    const float* b1   = (const float*)d_in[5];
    const float* e1   = (const float*)d_in[6];
    const float* m1w1 = (const float*)d_in[7];
    const float* m1b1 = (const float*)d_in[8];
    const float* m1w2 = (const float*)d_in[9];
    const float* m1b2 = (const float*)d_in[10];

    const float* W2   = (const float*)d_in[11];
    const float* b2   = (const float*)d_in[12];
    const float* e2   = (const float*)d_in[13];
    const float* m2w1 = (const float*)d_in[14];
    const float* m2b1 = (const float*)d_in[15];
    const float* m2w2 = (const float*)d_in[16];
    const float* m2b2 = (const float*)d_in[17];

    int nNodes = in_sizes[0] / ND;   // 50000
    int nEdges = in_sizes[1];        // 1600000
    int ntiles = (nNodes + 31) / 32; // 1563
    int Stot = ntiles * 256;         // 400128 segments (incl. padding nodes)
    int nQuads = ntiles * 64;

    // ---- workspace layout (~112 MB)
    unsigned short* agbf = (unsigned short*)d_ws;                 // N*512 bf16 = 51.2MB
    unsigned short* xhbf = agbf + (long)nNodes * 512;             // N*64 bf16 = 6.4MB
    unsigned short* wt1  = xhbf + (long)nNodes * ND;
    unsigned short* wt2  = wt1 + 64 * 512;
    unsigned short* wm11 = wt2 + 64 * 512;
    unsigned short* wm12 = wm11 + 64 * 64;
    unsigned short* wm21 = wm12 + 64 * 64;
    unsigned short* wm22 = wm21 + 64 * 64;
    uint2* bbufA  = (uint2*)(wm22 + 64 * 64);                     // 13.8MB
    uint2* bbufB  = bbufA + (long)NSLICE * CAPA;                  // 19.3MB
    int* cnts     = (int*)(bbufB + (long)NTILE_AL * CAPB);
    int* bcur     = cnts;                                         // 8
    int* tilecur  = cnts + NSLICE;                                // 1568
    int* tilebase = tilecur + NTILE_AL;                           // 1568
    int* offsets  = tilebase + NTILE_AL;                          // Stot+1
    int* perm     = offsets + (Stot + 256);                       // E ints = 6.4MB
    unsigned char* quadlist = (unsigned char*)(perm + nEdges);    // ntiles*256 B
    float* h    = (float*)d_out;   // layer-1 fp32 h aliases d_out
    float* outp = (float*)d_out;

    int fgrid = (ntiles + 3) / 4;    // 4 waves/block, 32 nodes/wave
    int n8 = nNodes * ND / 8;
    int cvtotal = 65536 + 16384 + n8;

    // ---- build per-segment CSR via LDS-staged two-level bucketing (all dense writes)
    zeroi_kernel<<<7, 256, 0, stream>>>(cnts, NSLICE + NTILE_AL);
    bucket8_kernel<<<782, 256, 0, stream>>>(esrc, edst, etyp, bcur, bbufA, nEdges);
    subbucket_kernel<<<320, 256, 0, stream>>>(bbufA, bcur, tilecur, bbufB);
    tilescan_kernel<<<1, 256, 0, stream>>>(tilecur, tilebase, offsets, NTILE_AL, ntiles, nEdges);
    tilesort_kernel<<<ntiles, 256, 0, stream>>>(bbufB, tilecur, tilebase, offsets, perm, quadlist);

    // ---- all weight/x converts in one launch
    convert_all_kernel<<<(cvtotal + 255) / 256, 256, 0, stream>>>(
        W1, W2, m1w1, m1w2, m2w1, m2w2, (const float4*)x,
        wt1, wt2, wm11, wm12, wm21, wm22, xhbf, n8);

    // ---- layer 1
    gather_kernel<<<2048, 256, 0, stream>>>(xhbf, offsets, perm, quadlist, agbf,
                                            nQuads, nNodes, nEdges - 1);
    fused_node_kernel<<<fgrid, 256, 0, stream>>>(agbf, wt1, x, e1, wm11, m1b1,
                                                 wm12, m1b2, b1, h, xhbf, nNodes);

    // ---- layer 2
    gather_kernel<<<2048, 256, 0, stream>>>(xhbf, offsets, perm, quadlist, agbf,
                                            nQuads, nNodes, nEdges - 1);
    fused_node_kernel<<<fgrid, 256, 0, stream>>>(agbf, wt2, h, e2, wm21, m2b1,
                                                 wm22, m2b2, b2, outp, nullptr, nNodes);
}

// Round 17
// 213.685 us; speedup vs baseline: 1.0876x; 1.0487x over previous
//
#include <hip/hip_runtime.h>

#define ND 64        // feature dim
#define NR 8         // num edge types
#define NSLICE 8     // dst slices (XCD count)
#define SLICE_NODES 6272   // 196*32; 8*6272 >= 50000
#define TPS 196      // tiles per slice (32 nodes each)
#define NTILE_AL 1568
#define CAPA 216064  // per-slice bucket capacity (mean 200704, ~35 sigma)
#define CAPB 1536    // per-tile bucket capacity (mean 1024, 16 sigma)
#define LPAD 66      // LDS transpose row stride (bank-conflict-free)

typedef __bf16 bf16x8 __attribute__((ext_vector_type(8)));
typedef float f32x4 __attribute__((ext_vector_type(4)));
typedef unsigned short us8 __attribute__((ext_vector_type(8)));

__device__ inline unsigned short bf16_rne(float f) {
    unsigned u = __float_as_uint(f);
    unsigned r = (u + 0x7FFFu + ((u >> 16) & 1u)) >> 16;
    return (unsigned short)r;
}
__device__ inline float bf16_to_f(unsigned short s) {
    return __uint_as_float(((unsigned)s) << 16);
}

// ---------------------------------------------------------------- zero ints
__global__ __launch_bounds__(256) void zeroi_kernel(int* __restrict__ p, int n) {
    int i = blockIdx.x * 256 + threadIdx.x;
    int stride = gridDim.x * 256;
    for (; i < n; i += stride) p[i] = 0;
}

// ---------------------------------------------------------------- A1: bucket edges into 8 dst-slices (proven R10)
__global__ __launch_bounds__(256) void bucket8_kernel(
    const int* __restrict__ src, const int* __restrict__ dst,
    const int* __restrict__ typ, int* __restrict__ bcur,
    uint2* __restrict__ bbufA, int nEdges)
{
    __shared__ uint2 outst[1024];
    __shared__ int lcnt[NSLICE];
    __shared__ int lbase[NSLICE];
    __shared__ int gbase[NSLICE];
    int tid = threadIdx.x;

    for (int base = blockIdx.x * 1024; base < nEdges; base += gridDim.x * 1024) {
        int bn = min(1024, nEdges - base);
        if (tid < NSLICE) lcnt[tid] = 0;
        __syncthreads();
        uint2 ent[4]; int eb[4], eo[4];
#pragma unroll
        for (int k = 0; k < 4; ++k) {
            int i = tid + k * 256;
            eb[k] = -1;
            if (i < bn) {
                int e = base + i;
                int d = dst[e];
                int s = d / SLICE_NODES;
                eb[k] = s;
                ent[k].x = (unsigned)src[e];
                ent[k].y = ((unsigned)s << 16) | ((unsigned)typ[e] << 13) |
                           (unsigned)(d - s * SLICE_NODES);
                eo[k] = atomicAdd(&lcnt[s], 1);
            }
        }
        __syncthreads();
        if (tid == 0) {
            int run = 0;
#pragma unroll
            for (int i = 0; i < NSLICE; ++i) { lbase[i] = run; run += lcnt[i]; }
        }
        if (tid < NSLICE && lcnt[tid] > 0) gbase[tid] = atomicAdd(&bcur[tid], lcnt[tid]);
        __syncthreads();
#pragma unroll
        for (int k = 0; k < 4; ++k)
            if (eb[k] >= 0) outst[lbase[eb[k]] + eo[k]] = ent[k];
        __syncthreads();
#pragma unroll
        for (int k = 0; k < 4; ++k) {
            int i = tid + k * 256;
            if (i < bn) {
                uint2 e = outst[i];
                int s = e.y >> 16;
                bbufA[(long)s * CAPA + gbase[s] + (i - lbase[s])] = e;
            }
        }
        __syncthreads();
    }
}

// ---------------------------------------------------------------- A2: per-slice re-bin into 196 node-tiles (proven R10)
__global__ __launch_bounds__(256) void subbucket_kernel(
    const uint2* __restrict__ bbufA, const int* __restrict__ bcur,
    int* __restrict__ tilecur, uint2* __restrict__ bbufB)
{
    __shared__ uint2 outst[2048];
    __shared__ int lcnt[TPS];
    __shared__ int lbase[TPS];
    __shared__ int gbase[TPS];
    __shared__ int scanbuf[256];
    int tid = threadIdx.x;
    int slice = blockIdx.x & 7;
    int chunk = blockIdx.x >> 3;
    int nchunk = gridDim.x >> 3;
    int n = bcur[slice];
    const uint2* in = bbufA + (long)slice * CAPA;
    int per = (n + nchunk - 1) / nchunk;
    int beg = chunk * per;
    int end = min(beg + per, n);

    for (int b0 = beg; b0 < end; b0 += 2048) {
        int bn = min(2048, end - b0);
        if (tid < TPS) lcnt[tid] = 0;
        __syncthreads();
        uint2 ent[8]; int eb[8], eo[8];
#pragma unroll
        for (int k = 0; k < 8; ++k) {
            int i = tid + k * 256;
            eb[k] = -1;
            if (i < bn) {
                ent[k] = in[b0 + i];
                int bin = (ent[k].y & 8191u) >> 5;
                eb[k] = bin;
                eo[k] = atomicAdd(&lcnt[bin], 1);
            }
        }
        __syncthreads();
        int v = (tid < TPS) ? lcnt[tid] : 0;
        scanbuf[tid] = v;
        __syncthreads();
        int xs = v;
        for (int off = 1; off < 256; off <<= 1) {
            int y = (tid >= off) ? scanbuf[tid - off] : 0;
            __syncthreads();
            xs += y;
            scanbuf[tid] = xs;
            __syncthreads();
        }
        if (tid < TPS) {
            lbase[tid] = xs - v;
            if (v > 0) gbase[tid] = atomicAdd(&tilecur[slice * TPS + tid], v);
        }
        __syncthreads();
#pragma unroll
        for (int k = 0; k < 8; ++k)
            if (eb[k] >= 0) outst[lbase[eb[k]] + eo[k]] = ent[k];
        __syncthreads();
#pragma unroll
        for (int k = 0; k < 8; ++k) {
            int i = tid + k * 256;
            if (i < bn) {
                uint2 e = outst[i];
                int bin = (e.y & 8191u) >> 5;
                bbufB[(long)(slice * TPS + bin) * CAPB + gbase[bin] + (i - lbase[bin])] = e;
            }
        }
        __syncthreads();
    }
}

// ---------------------------------------------------------------- tilescan: prefix over per-tile counts (1 block)
__global__ __launch_bounds__(256) void tilescan_kernel(
    const int* __restrict__ tilecur, int* __restrict__ tilebase,
    int* __restrict__ offsets, int ntAl, int ntUsed, int nEdges)
{
    __shared__ int lds[256];
    int tid = threadIdx.x;
    int v[7]; int lsum = 0;
#pragma unroll
    for (int k = 0; k < 7; ++k) {
        int i = tid * 7 + k;
        v[k] = (i < ntAl) ? tilecur[i] : 0;
        lsum += v[k];
    }
    lds[tid] = lsum;
    __syncthreads();
    int x = lsum;
    for (int off = 1; off < 256; off <<= 1) {
        int y = (tid >= off) ? lds[tid - off] : 0;
        __syncthreads();
        x += y;
        lds[tid] = x;
        __syncthreads();
    }
    int run = x - lsum;
#pragma unroll
    for (int k = 0; k < 7; ++k) {
        int i = tid * 7 + k;
        if (i < ntAl) tilebase[i] = run;
        run += v[k];
    }
    if (tid == 0) offsets[(long)ntUsed * 256] = nEdges;  // sentinel end
}

// ---------------------------------------------------------------- tilesort: per-tile LDS counting sort -> CSR
// + length-sorted segment order (quadlist) for balanced gather quads.
__global__ __launch_bounds__(256) void tilesort_kernel(
    const uint2* __restrict__ bbufB, const int* __restrict__ tilecur,
    const int* __restrict__ tilebase, int* __restrict__ offsets,
    int* __restrict__ perm, unsigned char* __restrict__ quadlist)
{
    __shared__ int outst[CAPB];
    __shared__ int lcnt[256];
    __shared__ int sbuf[256];
    __shared__ int cur[256];
    __shared__ int hist2[32];
    __shared__ int hcur2[32];
    __shared__ unsigned char qorder[256];
    int t = blockIdx.x;
    int tid = threadIdx.x;
    int n = tilecur[t];
    int base = tilebase[t];
    const uint2* buf = bbufB + (long)t * CAPB;

    lcnt[tid] = 0;
    __syncthreads();
    for (int i = tid; i < n; i += 256) {
        uint2 e = buf[i];
        int k = (((e.y >> 13) & 7) << 5) | (e.y & 31);   // r*32 + nl
        atomicAdd(&lcnt[k], 1);
    }
    __syncthreads();
    int v = lcnt[tid];
    sbuf[tid] = v;
    __syncthreads();
    int x = v;
    for (int off = 1; off < 256; off <<= 1) {
        int y = (tid >= off) ? sbuf[tid - off] : 0;
        __syncthreads();
        x += y;
        sbuf[tid] = x;
        __syncthreads();
    }
    int pfx = x - v;
    cur[tid] = pfx;
    offsets[(long)t * 256 + tid] = base + pfx;
    __syncthreads();
    for (int i = tid; i < n; i += 256) {
        uint2 e = buf[i];
        int k = (((e.y >> 13) & 7) << 5) | (e.y & 31);
        int pos = atomicAdd(&cur[k], 1);
        outst[pos] = (int)e.x;
    }
    __syncthreads();
    for (int i = tid; i < n; i += 256) perm[base + i] = outst[i];

    // ---- length-sorted segment order (32-bin counting sort; empty segs first)
    int len2 = min(v, 31);
    if (tid < 32) hist2[tid] = 0;
    __syncthreads();
    atomicAdd(&hist2[len2], 1);
    __syncthreads();
    if (tid == 0) {
        int run = 0;
#pragma unroll
        for (int i = 0; i < 32; ++i) { hcur2[i] = run; run += hist2[i]; }
    }
    __syncthreads();
    int sp = atomicAdd(&hcur2[len2], 1);
    qorder[sp] = (unsigned char)tid;
    __syncthreads();
    quadlist[((long)t << 8) + tid] = qorder[tid];
}

// ---------------------------------------------------------------- convert_all: wt1|wt2|wm11|wm12|wm21|wm22|xhbf in one launch
__global__ __launch_bounds__(256) void convert_all_kernel(
    const float* __restrict__ W1, const float* __restrict__ W2,
    const float* __restrict__ m1w1, const float* __restrict__ m1w2,
    const float* __restrict__ m2w1, const float* __restrict__ m2w2,
    const float4* __restrict__ x,
    unsigned short* __restrict__ wt1, unsigned short* __restrict__ wt2,
    unsigned short* __restrict__ wm11, unsigned short* __restrict__ wm12,
    unsigned short* __restrict__ wm21, unsigned short* __restrict__ wm22,
    unsigned short* __restrict__ xb, int n8)
{
    int idx = blockIdx.x * 256 + threadIdx.x;
    if (idx < 65536) {                      // wt: [64 o][512 k] = W[k][o]
        const float* W = (idx < 32768) ? W1 : W2;
        unsigned short* wt = (idx < 32768) ? wt1 : wt2;
        int i = idx & 32767;
        int o = i >> 9, k = i & 511;
        wt[i] = bf16_rne(W[(long)k * 64 + o]);
        return;
    }
    idx -= 65536;
    if (idx < 16384) {                      // wm: [64 o][64 k] = m[k][o]
        int which = idx >> 12;
        const float* m = (which == 0) ? m1w1 : (which == 1) ? m1w2
                       : (which == 2) ? m2w1 : m2w2;
        unsigned short* wm = (which == 0) ? wm11 : (which == 1) ? wm12
                           : (which == 2) ? wm21 : wm22;
        int i = idx & 4095;
        int o = i >> 6, k = i & 63;
        wm[i] = bf16_rne(m[k * 64 + o]);
        return;
    }
    idx -= 16384;
    if (idx < n8) {                         // x -> bf16 (8 elems/thread)
        float4 v0 = x[idx * 2], v1 = x[idx * 2 + 1];
        us8 o;
        o[0] = bf16_rne(v0.x); o[1] = bf16_rne(v0.y);
        o[2] = bf16_rne(v0.z); o[3] = bf16_rne(v0.w);
        o[4] = bf16_rne(v1.x); o[5] = bf16_rne(v1.y);
        o[6] = bf16_rne(v1.z); o[7] = bf16_rne(v1.w);
        *(us8*)(xb + (long)idx * 8) = o;
    }
}

// ---------------------------------------------------------------- quad processing (shared by gather)
__device__ __forceinline__ void process_quad(
    int q, int fl, const unsigned short* __restrict__ xb,
    const int* __restrict__ offsets, const int* __restrict__ perm,
    const unsigned char* __restrict__ quadlist,
    unsigned short* __restrict__ agbf, int nNodes, int permMax)
{
    int t = q >> 6;
    int ql = q & 63;
    uchar4 s4 = *(const uchar4*)(quadlist + ((long)t << 8) + (ql << 2));
    int sb = t << 8;
    int sid0 = s4.x, sid1 = s4.y, sid2 = s4.z, sid3 = s4.w;
    int b0 = offsets[sb + sid0], E0 = offsets[sb + sid0 + 1];
    int b1 = offsets[sb + sid1], E1 = offsets[sb + sid1 + 1];
    int b2 = offsets[sb + sid2], E2 = offsets[sb + sid2 + 1];
    int b3 = offsets[sb + sid3], E3 = offsets[sb + sid3 + 1];

    float a0[8], a1[8], a2[8], a3[8];
#pragma unroll
    for (int j = 0; j < 8; ++j) { a0[j] = 0.f; a1[j] = 0.f; a2[j] = 0.f; a3[j] = 0.f; }
    int p0 = b0, p1 = b1, p2 = b2, p3 = b3;

    while ((p0 < E0) | (p1 < E1) | (p2 < E2) | (p3 < E3)) {
        int q0 = min(p0, permMax);
        int q1 = min(p1, permMax);
        int q2 = min(p2, permMax);
        int q3 = min(p3, permMax);
        int i0 = perm[q0];
        int i1 = perm[q1];
        int i2 = perm[q2];
        int i3 = perm[q3];
        us8 v0 = *(const us8*)(xb + (long)i0 * ND + fl * 8);
        us8 v1 = *(const us8*)(xb + (long)i1 * ND + fl * 8);
        us8 v2 = *(const us8*)(xb + (long)i2 * ND + fl * 8);
        us8 v3 = *(const us8*)(xb + (long)i3 * ND + fl * 8);
        float m0 = (p0 < E0) ? 1.f : 0.f;
        float m1 = (p1 < E1) ? 1.f : 0.f;
        float m2 = (p2 < E2) ? 1.f : 0.f;
        float m3 = (p3 < E3) ? 1.f : 0.f;
#pragma unroll
        for (int j = 0; j < 8; ++j) {
            a0[j] = fmaf(m0, bf16_to_f(v0[j]), a0[j]);
            a1[j] = fmaf(m1, bf16_to_f(v1[j]), a1[j]);
            a2[j] = fmaf(m2, bf16_to_f(v2[j]), a2[j]);
            a3[j] = fmaf(m3, bf16_to_f(v3[j]), a3[j]);
        }
        p0 += (p0 < E0); p1 += (p1 < E1); p2 += (p2 < E2); p3 += (p3 < E3);
    }

    // each segment writes its own aligned 128B slice
    int nb = t << 5;
#define WR(sid, a)                                                          \
    {                                                                       \
        int node = nb | (sid & 31);                                         \
        if (node < nNodes) {                                                \
            us8 o;                                                          \
            _Pragma("unroll")                                               \
            for (int j = 0; j < 8; ++j) o[j] = bf16_rne(a[j]);              \
            *(us8*)(agbf + (long)node * 512 + (sid >> 5) * ND + fl * 8) = o; \
        }                                                                   \
    }
    WR(sid0, a0) WR(sid1, a1) WR(sid2, a2) WR(sid3, a3)
#undef WR
}

// ---------------------------------------------------------------- gather (folded-pair schedule over length-sorted quads)
// Quads are length-sorted within each tile (tilesort). Group g processes the
// PAIR {pr, nQuads-1-pr}: one short-rank + one long-rank quad -> per-group
// total work ~= 2x mean (fixes R16's inter-group tail imbalance; intra-quad
// balance retained).
__global__ __launch_bounds__(256) void gather_kernel(
    const unsigned short* __restrict__ xb, const int* __restrict__ offsets,
    const int* __restrict__ perm, const unsigned char* __restrict__ quadlist,
    unsigned short* __restrict__ agbf, int nQuads, int nNodes, int permMax)
{
    int tid = threadIdx.x;
    int gidx = (blockIdx.x * 256 + tid) >> 3;     // 8 lanes per group
    int nGroups = (gridDim.x * 256) >> 3;
    int fl = tid & 7;                             // lane's 8-feature slice
    int nPairs = nQuads >> 1;                     // nQuads is even (ntiles*64)

    for (int pr = gidx; pr < nPairs; pr += nGroups) {
        process_quad(pr, fl, xb, offsets, perm, quadlist, agbf, nNodes, permMax);
        process_quad(nQuads - 1 - pr, fl, xb, offsets, perm, quadlist, agbf, nNodes, permMax);
    }
}

// ---------------------------------------------------------------- fused node kernel: einsum + residual + MLP1 + relu + MLP2
__global__ __launch_bounds__(256) void fused_node_kernel(
    const unsigned short* __restrict__ agbf, const unsigned short* __restrict__ wt,
    const float* __restrict__ xin, const float* __restrict__ eps,
    const unsigned short* __restrict__ wm1t, const float* __restrict__ mb1,
    const unsigned short* __restrict__ wm2t, const float* __restrict__ mb2,
    const float* __restrict__ bias,
    float* __restrict__ out, unsigned short* __restrict__ out_bf, int nNodes)
{
    __shared__ float lt_all[4][32 * LPAD];
    int wv = threadIdx.x >> 6;
    int lane = threadIdx.x & 63;
    int wid = blockIdx.x * 4 + wv;
    int nbase = wid * 32;
    if (nbase >= nNodes) return;
    float* lt = lt_all[wv];

    int r16 = lane & 15;
    int kg  = lane >> 4;
    float epsv = 1.0f + eps[0];

    int n0 = nbase + r16;      if (n0 >= nNodes) n0 = nNodes - 1;
    int n1 = nbase + 16 + r16; if (n1 >= nNodes) n1 = nNodes - 1;

    // ---- phase 1: msgs = ag @ Wt^T (K=512)
    f32x4 acc[2][4];
#pragma unroll
    for (int m = 0; m < 2; ++m)
#pragma unroll
        for (int j = 0; j < 4; ++j) acc[m][j] = (f32x4){0.f, 0.f, 0.f, 0.f};
    {
        const unsigned short* a0p = agbf + (long)n0 * 512 + kg * 8;
        const unsigned short* a1p = agbf + (long)n1 * 512 + kg * 8;
        const unsigned short* bp  = wt + (long)r16 * 512 + kg * 8;
#pragma unroll 4
        for (int kk = 0; kk < 16; ++kk) {
            bf16x8 a0 = *(const bf16x8*)(a0p + kk * 32);
            bf16x8 a1 = *(const bf16x8*)(a1p + kk * 32);
#pragma unroll
            for (int j = 0; j < 4; ++j) {
                bf16x8 b = *(const bf16x8*)(bp + (long)j * 16 * 512 + kk * 32);
                acc[0][j] = __builtin_amdgcn_mfma_f32_16x16x32_bf16(a0, b, acc[0][j], 0, 0, 0);
                acc[1][j] = __builtin_amdgcn_mfma_f32_16x16x32_bf16(a1, b, acc[1][j], 0, 0, 0);
            }
        }
    }

    // ---- transpose msgs: C-layout regs -> LDS (row = m*16+kg*4+reg, col = j*16+r16)
#pragma unroll
    for (int m = 0; m < 2; ++m)
#pragma unroll
        for (int reg = 0; reg < 4; ++reg) {
            int row = m * 16 + kg * 4 + reg;
#pragma unroll
            for (int j = 0; j < 4; ++j)
                lt[row * LPAD + j * 16 + r16] = acc[m][j][reg];
        }
    asm volatile("s_waitcnt lgkmcnt(0)" ::: "memory");

    // ---- phase 2: h = (1+eps)*x + msgs; t = relu(h @ wm1t^T + mb1)  (K=64)
    f32x4 acc2[2][4];
#pragma unroll
    for (int m = 0; m < 2; ++m)
#pragma unroll
        for (int j = 0; j < 4; ++j) acc2[m][j] = (f32x4){0.f, 0.f, 0.f, 0.f};
#pragma unroll
    for (int m = 0; m < 2; ++m) {
        int rowl = m * 16 + r16;              // row within wave tile
        long nrow = (m == 0) ? n0 : n1;
#pragma unroll
        for (int kk = 0; kk < 2; ++kk) {
            int k0 = kk * 32 + kg * 8;
            float4 x0 = *(const float4*)(xin + nrow * ND + k0);
            float4 x1 = *(const float4*)(xin + nrow * ND + k0 + 4);
            float4 m0 = *(const float4*)(lt + rowl * LPAD + k0);
            float4 m1 = *(const float4*)(lt + rowl * LPAD + k0 + 4);
            us8 u;
            u[0] = bf16_rne(fmaf(epsv, x0.x, m0.x));
            u[1] = bf16_rne(fmaf(epsv, x0.y, m0.y));
            u[2] = bf16_rne(fmaf(epsv, x0.z, m0.z));
            u[3] = bf16_rne(fmaf(epsv, x0.w, m0.w));
            u[4] = bf16_rne(fmaf(epsv, x1.x, m1.x));
            u[5] = bf16_rne(fmaf(epsv, x1.y, m1.y));
            u[6] = bf16_rne(fmaf(epsv, x1.z, m1.z));
            u[7] = bf16_rne(fmaf(epsv, x1.w, m1.w));
            bf16x8 a = __builtin_bit_cast(bf16x8, u);
#pragma unroll
            for (int j = 0; j < 4; ++j) {
                bf16x8 b = *(const bf16x8*)(wm1t + (long)(j * 16 + r16) * ND + k0);
                acc2[m][j] = __builtin_amdgcn_mfma_f32_16x16x32_bf16(a, b, acc2[m][j], 0, 0, 0);
            }
        }
    }

    // ---- transpose t (with bias+relu): regs -> LDS
    asm volatile("s_waitcnt lgkmcnt(0)" ::: "memory");  // drain phase-2 reads before overwrite
#pragma unroll
    for (int m = 0; m < 2; ++m)
#pragma unroll
        for (int reg = 0; reg < 4; ++reg) {
            int row = m * 16 + kg * 4 + reg;
#pragma unroll
            for (int j = 0; j < 4; ++j) {
                int col = j * 16 + r16;
                lt[row * LPAD + col] = fmaxf(acc2[m][j][reg] + mb1[col], 0.f);
            }
        }
    asm volatile("s_waitcnt lgkmcnt(0)" ::: "memory");

    // ---- phase 3: out = t @ wm2t^T + mb2 + bias  (K=64)
    f32x4 acc3[2][4];
#pragma unroll
    for (int m = 0; m < 2; ++m)
#pragma unroll
        for (int j = 0; j < 4; ++j) acc3[m][j] = (f32x4){0.f, 0.f, 0.f, 0.f};
#pragma unroll
    for (int m = 0; m < 2; ++m) {
        int rowl = m * 16 + r16;
#pragma unroll
        for (int kk = 0; kk < 2; ++kk) {
            int k0 = kk * 32 + kg * 8;
            float4 t0 = *(const float4*)(lt + rowl * LPAD + k0);
            float4 t1 = *(const float4*)(lt + rowl * LPAD + k0 + 4);
            us8 u;
            u[0] = bf16_rne(t0.x); u[1] = bf16_rne(t0.y);
            u[2] = bf16_rne(t0.z); u[3] = bf16_rne(t0.w);
            u[4] = bf16_rne(t1.x); u[5] = bf16_rne(t1.y);
            u[6] = bf16_rne(t1.z); u[7] = bf16_rne(t1.w);
            bf16x8 a = __builtin_bit_cast(bf16x8, u);
#pragma unroll
            for (int j = 0; j < 4; ++j) {
                bf16x8 b = *(const bf16x8*)(wm2t + (long)(j * 16 + r16) * ND + k0);
                acc3[m][j] = __builtin_amdgcn_mfma_f32_16x16x32_bf16(a, b, acc3[m][j], 0, 0, 0);
            }
        }
    }

    // ---- epilogue: out (f32) + optional bf16 copy
#pragma unroll
    for (int m = 0; m < 2; ++m) {
#pragma unroll
        for (int reg = 0; reg < 4; ++reg) {
            int row = nbase + m * 16 + kg * 4 + reg;
            if (row < nNodes) {
#pragma unroll
                for (int j = 0; j < 4; ++j) {
                    int col = j * 16 + r16;
                    float v = acc3[m][j][reg] + mb2[col] + bias[col];
                    out[(long)row * ND + col] = v;
                    if (out_bf != nullptr)
                        out_bf[(long)row * ND + col] = bf16_rne(v);
                }
            }
        }
    }
}

// ---------------------------------------------------------------- launch
extern "C" void kernel_launch(void* const* d_in, const int* in_sizes, int n_in,
                              void* d_out, int out_size, void* d_ws, size_t ws_size,
                              hipStream_t stream) {
    const float* x    = (const float*)d_in[0];
    const int* esrc   = (const int*)d_in[1];
    const int* edst   = (const int*)d_in[2];
    const int* etyp   = (const int*)d_in[3];

    const float* W1   = (const float*)d_in[4];
    const float* b1   = (const float*)d_in[5];
    const float* e1   = (const float*)d_in[6];
    const float* m1w1 = (const float*)d_in[7];
    const float* m1b1 = (const float*)d_in[8];
    const float* m1w2 = (const float*)d_in[9];
    const float* m1b2 = (const float*)d_in[10];

    const float* W2   = (const float*)d_in[11];
    const float* b2   = (const float*)d_in[12];
    const float* e2   = (const float*)d_in[13];
    const float* m2w1 = (const float*)d_in[14];
    const float* m2b1 = (const float*)d_in[15];
    const float* m2w2 = (const float*)d_in[16];
    const float* m2b2 = (const float*)d_in[17];

    int nNodes = in_sizes[0] / ND;   // 50000
    int nEdges = in_sizes[1];        // 1600000
    int ntiles = (nNodes + 31) / 32; // 1563
    int Stot = ntiles * 256;         // 400128 segments (incl. padding nodes)
    int nQuads = ntiles * 64;

    // ---- workspace layout (~112 MB)
    unsigned short* agbf = (unsigned short*)d_ws;                 // N*512 bf16 = 51.2MB
    unsigned short* xhbf = agbf + (long)nNodes * 512;             // N*64 bf16 = 6.4MB
    unsigned short* wt1  = xhbf + (long)nNodes * ND;
    unsigned short* wt2  = wt1 + 64 * 512;
    unsigned short* wm11 = wt2 + 64 * 512;
    unsigned short* wm12 = wm11 + 64 * 64;
    unsigned short* wm21 = wm12 + 64 * 64;
    unsigned short* wm22 = wm21 + 64 * 64;
    uint2* bbufA  = (uint2*)(wm22 + 64 * 64);                     // 13.8MB
    uint2* bbufB  = bbufA + (long)NSLICE * CAPA;                  // 19.3MB
    int* cnts     = (int*)(bbufB + (long)NTILE_AL * CAPB);
    int* bcur     = cnts;                                         // 8
    int* tilecur  = cnts + NSLICE;                                // 1568
    int* tilebase = tilecur + NTILE_AL;                           // 1568
    int* offsets  = tilebase + NTILE_AL;                          // Stot+1
    int* perm     = offsets + (Stot + 256);                       // E ints = 6.4MB
    unsigned char* quadlist = (unsigned char*)(perm + nEdges);    // ntiles*256 B
    float* h    = (float*)d_out;   // layer-1 fp32 h aliases d_out
    float* outp = (float*)d_out;

    int fgrid = (ntiles + 3) / 4;    // 4 waves/block, 32 nodes/wave
    int n8 = nNodes * ND / 8;
    int cvtotal = 65536 + 16384 + n8;

    // ---- build per-segment CSR via LDS-staged two-level bucketing (all dense writes)
    zeroi_kernel<<<7, 256, 0, stream>>>(cnts, NSLICE + NTILE_AL);
    bucket8_kernel<<<782, 256, 0, stream>>>(esrc, edst, etyp, bcur, bbufA, nEdges);
    subbucket_kernel<<<320, 256, 0, stream>>>(bbufA, bcur, tilecur, bbufB);
    tilescan_kernel<<<1, 256, 0, stream>>>(tilecur, tilebase, offsets, NTILE_AL, ntiles, nEdges);
    tilesort_kernel<<<ntiles, 256, 0, stream>>>(bbufB, tilecur, tilebase, offsets, perm, quadlist);

    // ---- all weight/x converts in one launch
    convert_all_kernel<<<(cvtotal + 255) / 256, 256, 0, stream>>>(
        W1, W2, m1w1, m1w2, m2w1, m2w2, (const float4*)x,
        wt1, wt2, wm11, wm12, wm21, wm22, xhbf, n8);

    // ---- layer 1
    gather_kernel<<<2048, 256, 0, stream>>>(xhbf, offsets, perm, quadlist, agbf,
                                            nQuads, nNodes, nEdges - 1);
    fused_node_kernel<<<fgrid, 256, 0, stream>>>(agbf, wt1, x, e1, wm11, m1b1,
                                                 wm12, m1b2, b1, h, xhbf, nNodes);

    // ---- layer 2
    gather_kernel<<<2048, 256, 0, stream>>>(xhbf, offsets, perm, quadlist, agbf,
                                            nQuads, nNodes, nEdges - 1);
    fused_node_kernel<<<fgrid, 256, 0, stream>>>(agbf, wt2, h, e2, wm21, m2b1,
                                                 wm22, m2b2, b2, outp, nullptr, nNodes);
}

// Round 18
// 189.218 us; speedup vs baseline: 1.2283x; 1.1293x over previous
//
#include <hip/hip_runtime.h>

#define ND 64        // feature dim
#define NR 8         // num edge types
#define NSLICE 8     // dst slices (XCD count)
#define SLICE_NODES 6272   // 196*32; 8*6272 >= 50000
#define TPS 196      // tiles per slice (32 nodes each)
#define NTILE_AL 1568
#define CAPA 216064  // per-slice bucket capacity
#define CAPB 1536    // per-tile bucket capacity
#define LPAD 66      // LDS transpose row stride

typedef __bf16 bf16x8 __attribute__((ext_vector_type(8)));
typedef float f32x4 __attribute__((ext_vector_type(4)));
typedef unsigned short us8 __attribute__((ext_vector_type(8)));

__device__ inline unsigned short bf16_rne(float f) {
    unsigned u = __float_as_uint(f);
    unsigned r = (u + 0x7FFFu + ((u >> 16) & 1u)) >> 16;
    return (unsigned short)r;
}
__device__ inline float bf16_to_f(unsigned short s) {
    return __uint_as_float(((unsigned)s) << 16);
}

// ---------------------------------------------------------------- zero ints
__global__ __launch_bounds__(256) void zeroi_kernel(int* __restrict__ p, int n) {
    int i = blockIdx.x * 256 + threadIdx.x;
    int stride = gridDim.x * 256;
    for (; i < n; i += stride) p[i] = 0;
}

// ---------------------------------------------------------------- A1: bucket edges into 8 dst-slices (proven R10)
__global__ __launch_bounds__(256) void bucket8_kernel(
    const int* __restrict__ src, const int* __restrict__ dst,
    const int* __restrict__ typ, int* __restrict__ bcur,
    uint2* __restrict__ bbufA, int nEdges)
{
    __shared__ uint2 outst[1024];
    __shared__ int lcnt[NSLICE];
    __shared__ int lbase[NSLICE];
    __shared__ int gbase[NSLICE];
    int tid = threadIdx.x;

    for (int base = blockIdx.x * 1024; base < nEdges; base += gridDim.x * 1024) {
        int bn = min(1024, nEdges - base);
        if (tid < NSLICE) lcnt[tid] = 0;
        __syncthreads();
        uint2 ent[4]; int eb[4], eo[4];
#pragma unroll
        for (int k = 0; k < 4; ++k) {
            int i = tid + k * 256;
            eb[k] = -1;
            if (i < bn) {
                int e = base + i;
                int d = dst[e];
                int s = d / SLICE_NODES;
                eb[k] = s;
                ent[k].x = (unsigned)src[e];
                ent[k].y = ((unsigned)s << 16) | ((unsigned)typ[e] << 13) |
                           (unsigned)(d - s * SLICE_NODES);
                eo[k] = atomicAdd(&lcnt[s], 1);
            }
        }
        __syncthreads();
        if (tid == 0) {
            int run = 0;
#pragma unroll
            for (int i = 0; i < NSLICE; ++i) { lbase[i] = run; run += lcnt[i]; }
        }
        if (tid < NSLICE && lcnt[tid] > 0) gbase[tid] = atomicAdd(&bcur[tid], lcnt[tid]);
        __syncthreads();
#pragma unroll
        for (int k = 0; k < 4; ++k)
            if (eb[k] >= 0) outst[lbase[eb[k]] + eo[k]] = ent[k];
        __syncthreads();
#pragma unroll
        for (int k = 0; k < 4; ++k) {
            int i = tid + k * 256;
            if (i < bn) {
                uint2 e = outst[i];
                int s = e.y >> 16;
                bbufA[(long)s * CAPA + gbase[s] + (i - lbase[s])] = e;
            }
        }
        __syncthreads();
    }
}

// ---------------------------------------------------------------- A2: per-slice re-bin into 196 node-tiles (proven R10)
__global__ __launch_bounds__(256) void subbucket_kernel(
    const uint2* __restrict__ bbufA, const int* __restrict__ bcur,
    int* __restrict__ tilecur, uint2* __restrict__ bbufB)
{
    __shared__ uint2 outst[2048];
    __shared__ int lcnt[TPS];
    __shared__ int lbase[TPS];
    __shared__ int gbase[TPS];
    __shared__ int scanbuf[256];
    int tid = threadIdx.x;
    int slice = blockIdx.x & 7;
    int chunk = blockIdx.x >> 3;
    int nchunk = gridDim.x >> 3;
    int n = bcur[slice];
    const uint2* in = bbufA + (long)slice * CAPA;
    int per = (n + nchunk - 1) / nchunk;
    int beg = chunk * per;
    int end = min(beg + per, n);

    for (int b0 = beg; b0 < end; b0 += 2048) {
        int bn = min(2048, end - b0);
        if (tid < TPS) lcnt[tid] = 0;
        __syncthreads();
        uint2 ent[8]; int eb[8], eo[8];
#pragma unroll
        for (int k = 0; k < 8; ++k) {
            int i = tid + k * 256;
            eb[k] = -1;
            if (i < bn) {
                ent[k] = in[b0 + i];
                int bin = (ent[k].y & 8191u) >> 5;
                eb[k] = bin;
                eo[k] = atomicAdd(&lcnt[bin], 1);
            }
        }
        __syncthreads();
        int v = (tid < TPS) ? lcnt[tid] : 0;
        scanbuf[tid] = v;
        __syncthreads();
        int xs = v;
        for (int off = 1; off < 256; off <<= 1) {
            int y = (tid >= off) ? scanbuf[tid - off] : 0;
            __syncthreads();
            xs += y;
            scanbuf[tid] = xs;
            __syncthreads();
        }
        if (tid < TPS) {
            lbase[tid] = xs - v;
            if (v > 0) gbase[tid] = atomicAdd(&tilecur[slice * TPS + tid], v);
        }
        __syncthreads();
#pragma unroll
        for (int k = 0; k < 8; ++k)
            if (eb[k] >= 0) outst[lbase[eb[k]] + eo[k]] = ent[k];
        __syncthreads();
#pragma unroll
        for (int k = 0; k < 8; ++k) {
            int i = tid + k * 256;
            if (i < bn) {
                uint2 e = outst[i];
                int bin = (e.y & 8191u) >> 5;
                bbufB[(long)(slice * TPS + bin) * CAPB + gbase[bin] + (i - lbase[bin])] = e;
            }
        }
        __syncthreads();
    }
}

// ---------------------------------------------------------------- tilescan: prefix over per-tile counts (1 block)
__global__ __launch_bounds__(256) void tilescan_kernel(
    const int* __restrict__ tilecur, int* __restrict__ tilebase,
    int* __restrict__ offsets, int ntAl, int ntUsed, int nEdges)
{
    __shared__ int lds[256];
    int tid = threadIdx.x;
    int v[7]; int lsum = 0;
#pragma unroll
    for (int k = 0; k < 7; ++k) {
        int i = tid * 7 + k;
        v[k] = (i < ntAl) ? tilecur[i] : 0;
        lsum += v[k];
    }
    lds[tid] = lsum;
    __syncthreads();
    int x = lsum;
    for (int off = 1; off < 256; off <<= 1) {
        int y = (tid >= off) ? lds[tid - off] : 0;
        __syncthreads();
        x += y;
        lds[tid] = x;
        __syncthreads();
    }
    int run = x - lsum;
#pragma unroll
    for (int k = 0; k < 7; ++k) {
        int i = tid * 7 + k;
        if (i < ntAl) tilebase[i] = run;
        run += v[k];
    }
    if (tid == 0) offsets[(long)ntUsed * 256] = nEdges;  // sentinel end
}

// ---------------------------------------------------------------- tilesort: per-tile LDS counting sort -> CSR
// + length-sorted segment order (quadlist) for balanced gather quads.
__global__ __launch_bounds__(256) void tilesort_kernel(
    const uint2* __restrict__ bbufB, const int* __restrict__ tilecur,
    const int* __restrict__ tilebase, int* __restrict__ offsets,
    int* __restrict__ perm, unsigned char* __restrict__ quadlist)
{
    __shared__ int outst[CAPB];
    __shared__ int lcnt[256];
    __shared__ int sbuf[256];
    __shared__ int cur[256];
    __shared__ int hist2[32];
    __shared__ int hcur2[32];
    __shared__ unsigned char qorder[256];
    int t = blockIdx.x;
    int tid = threadIdx.x;
    int n = tilecur[t];
    int base = tilebase[t];
    const uint2* buf = bbufB + (long)t * CAPB;

    lcnt[tid] = 0;
    __syncthreads();
    for (int i = tid; i < n; i += 256) {
        uint2 e = buf[i];
        int k = (((e.y >> 13) & 7) << 5) | (e.y & 31);   // r*32 + nl
        atomicAdd(&lcnt[k], 1);
    }
    __syncthreads();
    int v = lcnt[tid];
    sbuf[tid] = v;
    __syncthreads();
    int x = v;
    for (int off = 1; off < 256; off <<= 1) {
        int y = (tid >= off) ? sbuf[tid - off] : 0;
        __syncthreads();
        x += y;
        sbuf[tid] = x;
        __syncthreads();
    }
    int pfx = x - v;
    cur[tid] = pfx;
    offsets[(long)t * 256 + tid] = base + pfx;
    __syncthreads();
    for (int i = tid; i < n; i += 256) {
        uint2 e = buf[i];
        int k = (((e.y >> 13) & 7) << 5) | (e.y & 31);
        int pos = atomicAdd(&cur[k], 1);
        outst[pos] = (int)e.x;
    }
    __syncthreads();
    for (int i = tid; i < n; i += 256) perm[base + i] = outst[i];

    // ---- length-sorted segment order (32-bin counting sort; empty segs first)
    int len2 = min(v, 31);
    if (tid < 32) hist2[tid] = 0;
    __syncthreads();
    atomicAdd(&hist2[len2], 1);
    __syncthreads();
    if (tid == 0) {
        int run = 0;
#pragma unroll
        for (int i = 0; i < 32; ++i) { hcur2[i] = run; run += hist2[i]; }
    }
    __syncthreads();
    int sp = atomicAdd(&hcur2[len2], 1);
    qorder[sp] = (unsigned char)tid;
    __syncthreads();
    quadlist[((long)t << 8) + tid] = qorder[tid];
}

// ---------------------------------------------------------------- convert_all
__global__ __launch_bounds__(256) void convert_all_kernel(
    const float* __restrict__ W1, const float* __restrict__ W2,
    const float* __restrict__ m1w1, const float* __restrict__ m1w2,
    const float* __restrict__ m2w1, const float* __restrict__ m2w2,
    const float4* __restrict__ x,
    unsigned short* __restrict__ wt1, unsigned short* __restrict__ wt2,
    unsigned short* __restrict__ wm11, unsigned short* __restrict__ wm12,
    unsigned short* __restrict__ wm21, unsigned short* __restrict__ wm22,
    unsigned short* __restrict__ xb, int n8)
{
    int idx = blockIdx.x * 256 + threadIdx.x;
    if (idx < 65536) {                      // wt: [64 o][512 k] = W[k][o]
        const float* W = (idx < 32768) ? W1 : W2;
        unsigned short* wt = (idx < 32768) ? wt1 : wt2;
        int i = idx & 32767;
        int o = i >> 9, k = i & 511;
        wt[i] = bf16_rne(W[(long)k * 64 + o]);
        return;
    }
    idx -= 65536;
    if (idx < 16384) {                      // wm: [64 o][64 k] = m[k][o]
        int which = idx >> 12;
        const float* m = (which == 0) ? m1w1 : (which == 1) ? m1w2
                       : (which == 2) ? m2w1 : m2w2;
        unsigned short* wm = (which == 0) ? wm11 : (which == 1) ? wm12
                           : (which == 2) ? wm21 : wm22;
        int i = idx & 4095;
        int o = i >> 6, k = i & 63;
        wm[i] = bf16_rne(m[k * 64 + o]);
        return;
    }
    idx -= 16384;
    if (idx < n8) {                         // x -> bf16 (8 elems/thread)
        float4 v0 = x[idx * 2], v1 = x[idx * 2 + 1];
        us8 o;
        o[0] = bf16_rne(v0.x); o[1] = bf16_rne(v0.y);
        o[2] = bf16_rne(v0.z); o[3] = bf16_rne(v0.w);
        o[4] = bf16_rne(v1.x); o[5] = bf16_rne(v1.y);
        o[6] = bf16_rne(v1.z); o[7] = bf16_rne(v1.w);
        *(us8*)(xb + (long)idx * 8) = o;
    }
}

// ---------------------------------------------------------------- quad -> LDS (gather phase of fused layer)
// Writes each segment's 128B row-slice into the swizzled LDS ag tile:
// slot(16B units) = r*8 + fl, phys = (r*8) | ((fl ^ nl) & 7).
__device__ __forceinline__ void process_quad_lds(
    int t, int ql, int fl, const unsigned short* __restrict__ xb,
    const int* __restrict__ offsets, const int* __restrict__ perm,
    const unsigned char* __restrict__ quadlist,
    unsigned short* ag_lds, int permMax)
{
    uchar4 s4 = *(const uchar4*)(quadlist + ((long)t << 8) + (ql << 2));
    int sb = t << 8;
    int sid0 = s4.x, sid1 = s4.y, sid2 = s4.z, sid3 = s4.w;
    int b0 = offsets[sb + sid0], E0 = offsets[sb + sid0 + 1];
    int b1 = offsets[sb + sid1], E1 = offsets[sb + sid1 + 1];
    int b2 = offsets[sb + sid2], E2 = offsets[sb + sid2 + 1];
    int b3 = offsets[sb + sid3], E3 = offsets[sb + sid3 + 1];

    float a0[8], a1[8], a2[8], a3[8];
#pragma unroll
    for (int j = 0; j < 8; ++j) { a0[j] = 0.f; a1[j] = 0.f; a2[j] = 0.f; a3[j] = 0.f; }
    int p0 = b0, p1 = b1, p2 = b2, p3 = b3;

    while ((p0 < E0) | (p1 < E1) | (p2 < E2) | (p3 < E3)) {
        int q0 = min(p0, permMax);
        int q1 = min(p1, permMax);
        int q2 = min(p2, permMax);
        int q3 = min(p3, permMax);
        int i0 = perm[q0];
        int i1 = perm[q1];
        int i2 = perm[q2];
        int i3 = perm[q3];
        us8 v0 = *(const us8*)(xb + (long)i0 * ND + fl * 8);
        us8 v1 = *(const us8*)(xb + (long)i1 * ND + fl * 8);
        us8 v2 = *(const us8*)(xb + (long)i2 * ND + fl * 8);
        us8 v3 = *(const us8*)(xb + (long)i3 * ND + fl * 8);
        float m0 = (p0 < E0) ? 1.f : 0.f;
        float m1 = (p1 < E1) ? 1.f : 0.f;
        float m2 = (p2 < E2) ? 1.f : 0.f;
        float m3 = (p3 < E3) ? 1.f : 0.f;
#pragma unroll
        for (int j = 0; j < 8; ++j) {
            a0[j] = fmaf(m0, bf16_to_f(v0[j]), a0[j]);
            a1[j] = fmaf(m1, bf16_to_f(v1[j]), a1[j]);
            a2[j] = fmaf(m2, bf16_to_f(v2[j]), a2[j]);
            a3[j] = fmaf(m3, bf16_to_f(v3[j]), a3[j]);
        }
        p0 += (p0 < E0); p1 += (p1 < E1); p2 += (p2 < E2); p3 += (p3 < E3);
    }

#define WRL(sid, a)                                                         \
    {                                                                       \
        int nl = sid & 31, r = sid >> 5;                                    \
        int phys = (r << 3) | ((fl ^ nl) & 7);                              \
        us8 o;                                                              \
        _Pragma("unroll")                                                   \
        for (int j = 0; j < 8; ++j) o[j] = bf16_rne(a[j]);                  \
        *(us8*)(ag_lds + nl * 512 + phys * 8) = o;                          \
    }
    WRL(sid0, a0) WRL(sid1, a1) WRL(sid2, a2) WRL(sid3, a3)
#undef WRL
}

// ---------------------------------------------------------------- fused layer: gather->LDS + einsum + residual + MLP1 + MLP2
// Block = one 32-node tile; 256 threads. Phase A: 32x 8-lane groups gather
// the tile's 256 segments into the swizzled 32KB LDS ag tile (folded pairs
// from the length-sorted quadlist). Phases 1-3: 4 waves split output cols
// (wave owns j=wv); A-frags from LDS (swizzled, ~2-way); msgs/t live in lt.
__global__ __launch_bounds__(256) void fused_layer_kernel(
    const unsigned short* __restrict__ xb, const int* __restrict__ offsets,
    const int* __restrict__ perm, const unsigned char* __restrict__ quadlist,
    const float* __restrict__ xin, const float* __restrict__ eps,
    const unsigned short* __restrict__ wt,
    const unsigned short* __restrict__ wm1t, const float* __restrict__ mb1,
    const unsigned short* __restrict__ wm2t, const float* __restrict__ mb2,
    const float* __restrict__ bias,
    float* __restrict__ out, unsigned short* __restrict__ out_bf,
    int nNodes, int permMax)
{
    __shared__ unsigned short ag_lds[32 * 512];   // 32 KB, swizzled
    __shared__ float lt[32 * LPAD];               // 8.4 KB
    int t = blockIdx.x;
    int tid = threadIdx.x;

    // ---- phase A: gather (folded pair of length-ranked quads per group)
    {
        int g = tid >> 3;
        int fl = tid & 7;
        process_quad_lds(t, g, fl, xb, offsets, perm, quadlist, ag_lds, permMax);
        process_quad_lds(t, 63 - g, fl, xb, offsets, perm, quadlist, ag_lds, permMax);
    }
    __syncthreads();

    int wv = tid >> 6;          // wave = output col quadrant j
    int lane = tid & 63;
    int r16 = lane & 15;
    int kg  = lane >> 4;
    int nbase = t * 32;
    float epsv = 1.0f + eps[0];
    int col = wv * 16 + r16;

    // ---- phase 1: msgs (j=wv quadrant), K=512 from LDS ag tile
    f32x4 acc[2];
    acc[0] = (f32x4){0.f, 0.f, 0.f, 0.f};
    acc[1] = (f32x4){0.f, 0.f, 0.f, 0.f};
    {
        const unsigned short* bp = wt + (long)col * 512 + kg * 8;
        int nl0 = r16, nl1 = 16 + r16;
#pragma unroll 4
        for (int kk = 0; kk < 16; ++kk) {
            int slot = kg + kk * 4;                       // 16B slot in [0,64)
            int p0 = (slot & 56) | ((slot ^ nl0) & 7);
            int p1 = (slot & 56) | ((slot ^ nl1) & 7);
            bf16x8 a0 = *(const bf16x8*)(ag_lds + nl0 * 512 + p0 * 8);
            bf16x8 a1 = *(const bf16x8*)(ag_lds + nl1 * 512 + p1 * 8);
            bf16x8 b = *(const bf16x8*)(bp + kk * 32);
            acc[0] = __builtin_amdgcn_mfma_f32_16x16x32_bf16(a0, b, acc[0], 0, 0, 0);
            acc[1] = __builtin_amdgcn_mfma_f32_16x16x32_bf16(a1, b, acc[1], 0, 0, 0);
        }
    }

    // ---- transpose msgs + residual: lt[row][col] = epsv*x + msgs
#pragma unroll
    for (int m = 0; m < 2; ++m)
#pragma unroll
        for (int reg = 0; reg < 4; ++reg) {
            int row = m * 16 + kg * 4 + reg;
            int node = nbase + row;
            int nc = (node < nNodes) ? node : (nNodes - 1);
            float xv = xin[(long)nc * ND + col];
            lt[row * LPAD + col] = fmaf(epsv, xv, acc[m][reg]);
        }
    __syncthreads();

    // ---- phase 2: t = relu(h @ wm1t^T + mb1), j=wv, K=64 from lt
    f32x4 acc2[2];
    acc2[0] = (f32x4){0.f, 0.f, 0.f, 0.f};
    acc2[1] = (f32x4){0.f, 0.f, 0.f, 0.f};
#pragma unroll
    for (int m = 0; m < 2; ++m) {
        int rowl = m * 16 + r16;
#pragma unroll
        for (int kk = 0; kk < 2; ++kk) {
            int k0 = kk * 32 + kg * 8;
            float4 h0 = *(const float4*)(lt + rowl * LPAD + k0);
            float4 h1 = *(const float4*)(lt + rowl * LPAD + k0 + 4);
            us8 u;
            u[0] = bf16_rne(h0.x); u[1] = bf16_rne(h0.y);
            u[2] = bf16_rne(h0.z); u[3] = bf16_rne(h0.w);
            u[4] = bf16_rne(h1.x); u[5] = bf16_rne(h1.y);
            u[6] = bf16_rne(h1.z); u[7] = bf16_rne(h1.w);
            bf16x8 a = __builtin_bit_cast(bf16x8, u);
            bf16x8 b = *(const bf16x8*)(wm1t + (long)col * ND + k0);
            acc2[m] = __builtin_amdgcn_mfma_f32_16x16x32_bf16(a, b, acc2[m], 0, 0, 0);
        }
    }
    __syncthreads();   // phase-2 lt reads complete before overwrite

    // ---- write t (bias + relu) into lt
#pragma unroll
    for (int m = 0; m < 2; ++m)
#pragma unroll
        for (int reg = 0; reg < 4; ++reg) {
            int row = m * 16 + kg * 4 + reg;
            lt[row * LPAD + col] = fmaxf(acc2[m][reg] + mb1[col], 0.f);
        }
    __syncthreads();

    // ---- phase 3: out = t @ wm2t^T + mb2 + bias, j=wv
    f32x4 acc3[2];
    acc3[0] = (f32x4){0.f, 0.f, 0.f, 0.f};
    acc3[1] = (f32x4){0.f, 0.f, 0.f, 0.f};
#pragma unroll
    for (int m = 0; m < 2; ++m) {
        int rowl = m * 16 + r16;
#pragma unroll
        for (int kk = 0; kk < 2; ++kk) {
            int k0 = kk * 32 + kg * 8;
            float4 t0 = *(const float4*)(lt + rowl * LPAD + k0);
            float4 t1 = *(const float4*)(lt + rowl * LPAD + k0 + 4);
            us8 u;
            u[0] = bf16_rne(t0.x); u[1] = bf16_rne(t0.y);
            u[2] = bf16_rne(t0.z); u[3] = bf16_rne(t0.w);
            u[4] = bf16_rne(t1.x); u[5] = bf16_rne(t1.y);
            u[6] = bf16_rne(t1.z); u[7] = bf16_rne(t1.w);
            bf16x8 a = __builtin_bit_cast(bf16x8, u);
            bf16x8 b = *(const bf16x8*)(wm2t + (long)col * ND + k0);
            acc3[m] = __builtin_amdgcn_mfma_f32_16x16x32_bf16(a, b, acc3[m], 0, 0, 0);
        }
    }

    // ---- epilogue
    float badd = mb2[col] + bias[col];
#pragma unroll
    for (int m = 0; m < 2; ++m)
#pragma unroll
        for (int reg = 0; reg < 4; ++reg) {
            int row = nbase + m * 16 + kg * 4 + reg;
            if (row < nNodes) {
                float v = acc3[m][reg] + badd;
                out[(long)row * ND + col] = v;
                if (out_bf != nullptr)
                    out_bf[(long)row * ND + col] = bf16_rne(v);
            }
        }
}

// ---------------------------------------------------------------- launch
extern "C" void kernel_launch(void* const* d_in, const int* in_sizes, int n_in,
                              void* d_out, int out_size, void* d_ws, size_t ws_size,
                              hipStream_t stream) {
    const float* x    = (const float*)d_in[0];
    const int* esrc   = (const int*)d_in[1];
    const int* edst   = (const int*)d_in[2];
    const int* etyp   = (const int*)d_in[3];

    const float* W1   = (const float*)d_in[4];
    const float* b1   = (const float*)d_in[5];
    const float* e1   = (const float*)d_in[6];
    const float* m1w1 = (const float*)d_in[7];
    const float* m1b1 = (const float*)d_in[8];
    const float* m1w2 = (const float*)d_in[9];
    const float* m1b2 = (const float*)d_in[10];

    const float* W2   = (const float*)d_in[11];
    const float* b2   = (const float*)d_in[12];
    const float* e2   = (const float*)d_in[13];
    const float* m2w1 = (const float*)d_in[14];
    const float* m2b1 = (const float*)d_in[15];
    const float* m2w2 = (const float*)d_in[16];
    const float* m2b2 = (const float*)d_in[17];

    int nNodes = in_sizes[0] / ND;   // 50000
    int nEdges = in_sizes[1];        // 1600000
    int ntiles = (nNodes + 31) / 32; // 1563
    int Stot = ntiles * 256;

    // ---- workspace layout
    unsigned short* xhbf = (unsigned short*)d_ws;                 // N*64 bf16 (x)
    unsigned short* hbf2 = xhbf + (long)nNodes * ND;              // N*64 bf16 (h)
    unsigned short* wt1  = hbf2 + (long)nNodes * ND;
    unsigned short* wt2  = wt1 + 64 * 512;
    unsigned short* wm11 = wt2 + 64 * 512;
    unsigned short* wm12 = wm11 + 64 * 64;
    unsigned short* wm21 = wm12 + 64 * 64;
    unsigned short* wm22 = wm21 + 64 * 64;
    uint2* bbufA  = (uint2*)(wm22 + 64 * 64);                     // 13.8MB
    uint2* bbufB  = bbufA + (long)NSLICE * CAPA;                  // 19.3MB
    int* cnts     = (int*)(bbufB + (long)NTILE_AL * CAPB);
    int* bcur     = cnts;                                         // 8
    int* tilecur  = cnts + NSLICE;                                // 1568
    int* tilebase = tilecur + NTILE_AL;                           // 1568
    int* offsets  = tilebase + NTILE_AL;                          // Stot+1
    int* perm     = offsets + (Stot + 256);                       // E ints
    unsigned char* quadlist = (unsigned char*)(perm + nEdges);    // ntiles*256 B
    float* h    = (float*)d_out;   // layer-1 fp32 h aliases d_out
    float* outp = (float*)d_out;

    int n8 = nNodes * ND / 8;
    int cvtotal = 65536 + 16384 + n8;

    // ---- build per-segment CSR via LDS-staged two-level bucketing
    zeroi_kernel<<<7, 256, 0, stream>>>(cnts, NSLICE + NTILE_AL);
    bucket8_kernel<<<782, 256, 0, stream>>>(esrc, edst, etyp, bcur, bbufA, nEdges);
    subbucket_kernel<<<320, 256, 0, stream>>>(bbufA, bcur, tilecur, bbufB);
    tilescan_kernel<<<1, 256, 0, stream>>>(tilecur, tilebase, offsets, NTILE_AL, ntiles, nEdges);
    tilesort_kernel<<<ntiles, 256, 0, stream>>>(bbufB, tilecur, tilebase, offsets, perm, quadlist);

    // ---- all weight/x converts in one launch
    convert_all_kernel<<<(cvtotal + 255) / 256, 256, 0, stream>>>(
        W1, W2, m1w1, m1w2, m2w1, m2w2, (const float4*)x,
        wt1, wt2, wm11, wm12, wm21, wm22, xhbf, n8);

    // ---- layer 1 (reads xhbf, writes h + hbf2)
    fused_layer_kernel<<<ntiles, 256, 0, stream>>>(
        xhbf, offsets, perm, quadlist, x, e1, wt1, wm11, m1b1, wm12, m1b2, b1,
        h, hbf2, nNodes, nEdges - 1);

    // ---- layer 2 (reads hbf2, writes out)
    fused_layer_kernel<<<ntiles, 256, 0, stream>>>(
        hbf2, offsets, perm, quadlist, h, e2, wt2, wm21, m2b1, wm22, m2b2, b2,
        outp, nullptr, nNodes, nEdges - 1);
}

// Round 19
// 178.035 us; speedup vs baseline: 1.3054x; 1.0628x over previous
//
#include <hip/hip_runtime.h>

#define ND 64        // feature dim
#define NR 8         // num edge types
#define NSLICE 8     // dst slices (XCD count)
#define SLICE_NODES 6272   // 196*32; 8*6272 >= 50000
#define TPS 196      // tiles per slice (32 nodes each)
#define NTILE_AL 1568
#define CAPA 216064  // per-slice bucket capacity
#define CAPB 1536    // per-tile bucket capacity
#define LPAD 66      // LDS transpose row stride

typedef __bf16 bf16x8 __attribute__((ext_vector_type(8)));
typedef float f32x4 __attribute__((ext_vector_type(4)));
typedef unsigned short us8 __attribute__((ext_vector_type(8)));

__device__ inline unsigned short bf16_rne(float f) {
    unsigned u = __float_as_uint(f);
    unsigned r = (u + 0x7FFFu + ((u >> 16) & 1u)) >> 16;
    return (unsigned short)r;
}
__device__ inline float bf16_to_f(unsigned short s) {
    return __uint_as_float(((unsigned)s) << 16);
}

// ---------------------------------------------------------------- zero ints
__global__ __launch_bounds__(256) void zeroi_kernel(int* __restrict__ p, int n) {
    int i = blockIdx.x * 256 + threadIdx.x;
    int stride = gridDim.x * 256;
    for (; i < n; i += stride) p[i] = 0;
}

// ---------------------------------------------------------------- A1: bucket edges into 8 dst-slices (proven R10)
__global__ __launch_bounds__(256) void bucket8_kernel(
    const int* __restrict__ src, const int* __restrict__ dst,
    const int* __restrict__ typ, int* __restrict__ bcur,
    uint2* __restrict__ bbufA, int nEdges)
{
    __shared__ uint2 outst[1024];
    __shared__ int lcnt[NSLICE];
    __shared__ int lbase[NSLICE];
    __shared__ int gbase[NSLICE];
    int tid = threadIdx.x;

    for (int base = blockIdx.x * 1024; base < nEdges; base += gridDim.x * 1024) {
        int bn = min(1024, nEdges - base);
        if (tid < NSLICE) lcnt[tid] = 0;
        __syncthreads();
        uint2 ent[4]; int eb[4], eo[4];
#pragma unroll
        for (int k = 0; k < 4; ++k) {
            int i = tid + k * 256;
            eb[k] = -1;
            if (i < bn) {
                int e = base + i;
                int d = dst[e];
                int s = d / SLICE_NODES;
                eb[k] = s;
                ent[k].x = (unsigned)src[e];
                ent[k].y = ((unsigned)s << 16) | ((unsigned)typ[e] << 13) |
                           (unsigned)(d - s * SLICE_NODES);
                eo[k] = atomicAdd(&lcnt[s], 1);
            }
        }
        __syncthreads();
        if (tid == 0) {
            int run = 0;
#pragma unroll
            for (int i = 0; i < NSLICE; ++i) { lbase[i] = run; run += lcnt[i]; }
        }
        if (tid < NSLICE && lcnt[tid] > 0) gbase[tid] = atomicAdd(&bcur[tid], lcnt[tid]);
        __syncthreads();
#pragma unroll
        for (int k = 0; k < 4; ++k)
            if (eb[k] >= 0) outst[lbase[eb[k]] + eo[k]] = ent[k];
        __syncthreads();
#pragma unroll
        for (int k = 0; k < 4; ++k) {
            int i = tid + k * 256;
            if (i < bn) {
                uint2 e = outst[i];
                int s = e.y >> 16;
                bbufA[(long)s * CAPA + gbase[s] + (i - lbase[s])] = e;
            }
        }
        __syncthreads();
    }
}

// ---------------------------------------------------------------- A2: per-slice re-bin into 196 node-tiles (proven R10)
__global__ __launch_bounds__(256) void subbucket_kernel(
    const uint2* __restrict__ bbufA, const int* __restrict__ bcur,
    int* __restrict__ tilecur, uint2* __restrict__ bbufB)
{
    __shared__ uint2 outst[2048];
    __shared__ int lcnt[TPS];
    __shared__ int lbase[TPS];
    __shared__ int gbase[TPS];
    __shared__ int scanbuf[256];
    int tid = threadIdx.x;
    int slice = blockIdx.x & 7;
    int chunk = blockIdx.x >> 3;
    int nchunk = gridDim.x >> 3;
    int n = bcur[slice];
    const uint2* in = bbufA + (long)slice * CAPA;
    int per = (n + nchunk - 1) / nchunk;
    int beg = chunk * per;
    int end = min(beg + per, n);

    for (int b0 = beg; b0 < end; b0 += 2048) {
        int bn = min(2048, end - b0);
        if (tid < TPS) lcnt[tid] = 0;
        __syncthreads();
        uint2 ent[8]; int eb[8], eo[8];
#pragma unroll
        for (int k = 0; k < 8; ++k) {
            int i = tid + k * 256;
            eb[k] = -1;
            if (i < bn) {
                ent[k] = in[b0 + i];
                int bin = (ent[k].y & 8191u) >> 5;
                eb[k] = bin;
                eo[k] = atomicAdd(&lcnt[bin], 1);
            }
        }
        __syncthreads();
        int v = (tid < TPS) ? lcnt[tid] : 0;
        scanbuf[tid] = v;
        __syncthreads();
        int xs = v;
        for (int off = 1; off < 256; off <<= 1) {
            int y = (tid >= off) ? scanbuf[tid - off] : 0;
            __syncthreads();
            xs += y;
            scanbuf[tid] = xs;
            __syncthreads();
        }
        if (tid < TPS) {
            lbase[tid] = xs - v;
            if (v > 0) gbase[tid] = atomicAdd(&tilecur[slice * TPS + tid], v);
        }
        __syncthreads();
#pragma unroll
        for (int k = 0; k < 8; ++k)
            if (eb[k] >= 0) outst[lbase[eb[k]] + eo[k]] = ent[k];
        __syncthreads();
#pragma unroll
        for (int k = 0; k < 8; ++k) {
            int i = tid + k * 256;
            if (i < bn) {
                uint2 e = outst[i];
                int bin = (e.y & 8191u) >> 5;
                bbufB[(long)(slice * TPS + bin) * CAPB + gbase[bin] + (i - lbase[bin])] = e;
            }
        }
        __syncthreads();
    }
}

// ---------------------------------------------------------------- tilescan: prefix over per-tile counts (1 block)
__global__ __launch_bounds__(256) void tilescan_kernel(
    const int* __restrict__ tilecur, int* __restrict__ tilebase,
    int* __restrict__ offsets, int ntAl, int ntUsed, int nEdges)
{
    __shared__ int lds[256];
    int tid = threadIdx.x;
    int v[7]; int lsum = 0;
#pragma unroll
    for (int k = 0; k < 7; ++k) {
        int i = tid * 7 + k;
        v[k] = (i < ntAl) ? tilecur[i] : 0;
        lsum += v[k];
    }
    lds[tid] = lsum;
    __syncthreads();
    int x = lsum;
    for (int off = 1; off < 256; off <<= 1) {
        int y = (tid >= off) ? lds[tid - off] : 0;
        __syncthreads();
        x += y;
        lds[tid] = x;
        __syncthreads();
    }
    int run = x - lsum;
#pragma unroll
    for (int k = 0; k < 7; ++k) {
        int i = tid * 7 + k;
        if (i < ntAl) tilebase[i] = run;
        run += v[k];
    }
    if (tid == 0) offsets[(long)ntUsed * 256] = nEdges;  // sentinel end
}

// ---------------------------------------------------------------- tilesort: per-tile LDS counting sort -> CSR
// + length-sorted segment order (quadlist) for balanced gather quads.
__global__ __launch_bounds__(256) void tilesort_kernel(
    const uint2* __restrict__ bbufB, const int* __restrict__ tilecur,
    const int* __restrict__ tilebase, int* __restrict__ offsets,
    int* __restrict__ perm, unsigned char* __restrict__ quadlist)
{
    __shared__ int outst[CAPB];
    __shared__ int lcnt[256];
    __shared__ int sbuf[256];
    __shared__ int cur[256];
    __shared__ int hist2[32];
    __shared__ int hcur2[32];
    __shared__ unsigned char qorder[256];
    int t = blockIdx.x;
    int tid = threadIdx.x;
    int n = tilecur[t];
    int base = tilebase[t];
    const uint2* buf = bbufB + (long)t * CAPB;

    lcnt[tid] = 0;
    __syncthreads();
    for (int i = tid; i < n; i += 256) {
        uint2 e = buf[i];
        int k = (((e.y >> 13) & 7) << 5) | (e.y & 31);   // r*32 + nl
        atomicAdd(&lcnt[k], 1);
    }
    __syncthreads();
    int v = lcnt[tid];
    sbuf[tid] = v;
    __syncthreads();
    int x = v;
    for (int off = 1; off < 256; off <<= 1) {
        int y = (tid >= off) ? sbuf[tid - off] : 0;
        __syncthreads();
        x += y;
        sbuf[tid] = x;
        __syncthreads();
    }
    int pfx = x - v;
    cur[tid] = pfx;
    offsets[(long)t * 256 + tid] = base + pfx;
    __syncthreads();
    for (int i = tid; i < n; i += 256) {
        uint2 e = buf[i];
        int k = (((e.y >> 13) & 7) << 5) | (e.y & 31);
        int pos = atomicAdd(&cur[k], 1);
        outst[pos] = (int)e.x;
    }
    __syncthreads();
    for (int i = tid; i < n; i += 256) perm[base + i] = outst[i];

    // ---- length-sorted segment order (32-bin counting sort; empty segs first)
    int len2 = min(v, 31);
    if (tid < 32) hist2[tid] = 0;
    __syncthreads();
    atomicAdd(&hist2[len2], 1);
    __syncthreads();
    if (tid == 0) {
        int run = 0;
#pragma unroll
        for (int i = 0; i < 32; ++i) { hcur2[i] = run; run += hist2[i]; }
    }
    __syncthreads();
    int sp = atomicAdd(&hcur2[len2], 1);
    qorder[sp] = (unsigned char)tid;
    __syncthreads();
    quadlist[((long)t << 8) + tid] = qorder[tid];
}

// ---------------------------------------------------------------- convert_all
__global__ __launch_bounds__(256) void convert_all_kernel(
    const float* __restrict__ W1, const float* __restrict__ W2,
    const float* __restrict__ m1w1, const float* __restrict__ m1w2,
    const float* __restrict__ m2w1, const float* __restrict__ m2w2,
    const float4* __restrict__ x,
    unsigned short* __restrict__ wt1, unsigned short* __restrict__ wt2,
    unsigned short* __restrict__ wm11, unsigned short* __restrict__ wm12,
    unsigned short* __restrict__ wm21, unsigned short* __restrict__ wm22,
    unsigned short* __restrict__ xb, int n8)
{
    int idx = blockIdx.x * 256 + threadIdx.x;
    if (idx < 65536) {                      // wt: [64 o][512 k] = W[k][o]
        const float* W = (idx < 32768) ? W1 : W2;
        unsigned short* wt = (idx < 32768) ? wt1 : wt2;
        int i = idx & 32767;
        int o = i >> 9, k = i & 511;
        wt[i] = bf16_rne(W[(long)k * 64 + o]);
        return;
    }
    idx -= 65536;
    if (idx < 16384) {                      // wm: [64 o][64 k] = m[k][o]
        int which = idx >> 12;
        const float* m = (which == 0) ? m1w1 : (which == 1) ? m1w2
                       : (which == 2) ? m2w1 : m2w2;
        unsigned short* wm = (which == 0) ? wm11 : (which == 1) ? wm12
                           : (which == 2) ? wm21 : wm22;
        int i = idx & 4095;
        int o = i >> 6, k = i & 63;
        wm[i] = bf16_rne(m[k * 64 + o]);
        return;
    }
    idx -= 16384;
    if (idx < n8) {                         // x -> bf16 (8 elems/thread)
        float4 v0 = x[idx * 2], v1 = x[idx * 2 + 1];
        us8 o;
        o[0] = bf16_rne(v0.x); o[1] = bf16_rne(v0.y);
        o[2] = bf16_rne(v0.z); o[3] = bf16_rne(v0.w);
        o[4] = bf16_rne(v1.x); o[5] = bf16_rne(v1.y);
        o[6] = bf16_rne(v1.z); o[7] = bf16_rne(v1.w);
        *(us8*)(xb + (long)idx * 8) = o;
    }
}

// ---------------------------------------------------------------- quad -> LDS (gather phase of fused layer)
// Writes each segment's 128B row-slice into the swizzled LDS ag tile:
// slot(16B units) = r*8 + fl, phys = (r*8) | ((fl ^ nl) & 7).
__device__ __forceinline__ void process_quad_lds(
    int t, int ql, int fl, const unsigned short* __restrict__ xb,
    const int* __restrict__ offsets, const int* __restrict__ perm,
    const unsigned char* __restrict__ quadlist,
    unsigned short* ag_lds, int permMax)
{
    uchar4 s4 = *(const uchar4*)(quadlist + ((long)t << 8) + (ql << 2));
    int sb = t << 8;
    int sid0 = s4.x, sid1 = s4.y, sid2 = s4.z, sid3 = s4.w;
    int b0 = offsets[sb + sid0], E0 = offsets[sb + sid0 + 1];
    int b1 = offsets[sb + sid1], E1 = offsets[sb + sid1 + 1];
    int b2 = offsets[sb + sid2], E2 = offsets[sb + sid2 + 1];
    int b3 = offsets[sb + sid3], E3 = offsets[sb + sid3 + 1];

    float a0[8], a1[8], a2[8], a3[8];
#pragma unroll
    for (int j = 0; j < 8; ++j) { a0[j] = 0.f; a1[j] = 0.f; a2[j] = 0.f; a3[j] = 0.f; }
    int p0 = b0, p1 = b1, p2 = b2, p3 = b3;

    while ((p0 < E0) | (p1 < E1) | (p2 < E2) | (p3 < E3)) {
        int q0 = min(p0, permMax);
        int q1 = min(p1, permMax);
        int q2 = min(p2, permMax);
        int q3 = min(p3, permMax);
        int i0 = perm[q0];
        int i1 = perm[q1];
        int i2 = perm[q2];
        int i3 = perm[q3];
        us8 v0 = *(const us8*)(xb + (long)i0 * ND + fl * 8);
        us8 v1 = *(const us8*)(xb + (long)i1 * ND + fl * 8);
        us8 v2 = *(const us8*)(xb + (long)i2 * ND + fl * 8);
        us8 v3 = *(const us8*)(xb + (long)i3 * ND + fl * 8);
        float m0 = (p0 < E0) ? 1.f : 0.f;
        float m1 = (p1 < E1) ? 1.f : 0.f;
        float m2 = (p2 < E2) ? 1.f : 0.f;
        float m3 = (p3 < E3) ? 1.f : 0.f;
#pragma unroll
        for (int j = 0; j < 8; ++j) {
            a0[j] = fmaf(m0, bf16_to_f(v0[j]), a0[j]);
            a1[j] = fmaf(m1, bf16_to_f(v1[j]), a1[j]);
            a2[j] = fmaf(m2, bf16_to_f(v2[j]), a2[j]);
            a3[j] = fmaf(m3, bf16_to_f(v3[j]), a3[j]);
        }
        p0 += (p0 < E0); p1 += (p1 < E1); p2 += (p2 < E2); p3 += (p3 < E3);
    }

#define WRL(sid, a)                                                         \
    {                                                                       \
        int nl = sid & 31, r = sid >> 5;                                    \
        int phys = (r << 3) | ((fl ^ nl) & 7);                              \
        us8 o;                                                              \
        _Pragma("unroll")                                                   \
        for (int j = 0; j < 8; ++j) o[j] = bf16_rne(a[j]);                  \
        *(us8*)(ag_lds + nl * 512 + phys * 8) = o;                          \
    }
    WRL(sid0, a0) WRL(sid1, a1) WRL(sid2, a2) WRL(sid3, a3)
#undef WRL
}

// ---------------------------------------------------------------- fused layer: gather->LDS + einsum + residual + MLP1 + MLP2
// Block = one 32-node tile; 256 threads. Phase A gathers into the swizzled
// 32KB LDS ag tile; phases 1-3 run MFMA per output-col quadrant. lt ALIASES
// ag_lds (ag is dead after phase-1 reads; a barrier separates reads from the
// overwrite) -> LDS block = 32KB -> 5 blocks/CU (was 3) for latency hiding.
__global__ __launch_bounds__(256) void fused_layer_kernel(
    const unsigned short* __restrict__ xb, const int* __restrict__ offsets,
    const int* __restrict__ perm, const unsigned char* __restrict__ quadlist,
    const float* __restrict__ xin, const float* __restrict__ eps,
    const unsigned short* __restrict__ wt,
    const unsigned short* __restrict__ wm1t, const float* __restrict__ mb1,
    const unsigned short* __restrict__ wm2t, const float* __restrict__ mb2,
    const float* __restrict__ bias,
    float* __restrict__ out, unsigned short* __restrict__ out_bf,
    int nNodes, int permMax)
{
    __shared__ unsigned short ag_lds[32 * 512];   // 32 KB, swizzled
    float* lt = (float*)ag_lds;                   // ALIAS: valid after post-phase-1 barrier
    int t = blockIdx.x;
    int tid = threadIdx.x;

    // ---- phase A: gather (folded pair of length-ranked quads per group)
    {
        int g = tid >> 3;
        int fl = tid & 7;
        process_quad_lds(t, g, fl, xb, offsets, perm, quadlist, ag_lds, permMax);
        process_quad_lds(t, 63 - g, fl, xb, offsets, perm, quadlist, ag_lds, permMax);
    }
    __syncthreads();

    int wv = tid >> 6;          // wave = output col quadrant j
    int lane = tid & 63;
    int r16 = lane & 15;
    int kg  = lane >> 4;
    int nbase = t * 32;
    float epsv = 1.0f + eps[0];
    int col = wv * 16 + r16;

    // ---- phase 1: msgs (j=wv quadrant), K=512 from LDS ag tile
    f32x4 acc[2];
    acc[0] = (f32x4){0.f, 0.f, 0.f, 0.f};
    acc[1] = (f32x4){0.f, 0.f, 0.f, 0.f};
    {
        const unsigned short* bp = wt + (long)col * 512 + kg * 8;
        int nl0 = r16, nl1 = 16 + r16;
#pragma unroll 4
        for (int kk = 0; kk < 16; ++kk) {
            int slot = kg + kk * 4;                       // 16B slot in [0,64)
            int p0 = (slot & 56) | ((slot ^ nl0) & 7);
            int p1 = (slot & 56) | ((slot ^ nl1) & 7);
            bf16x8 a0 = *(const bf16x8*)(ag_lds + nl0 * 512 + p0 * 8);
            bf16x8 a1 = *(const bf16x8*)(ag_lds + nl1 * 512 + p1 * 8);
            bf16x8 b = *(const bf16x8*)(bp + kk * 32);
            acc[0] = __builtin_amdgcn_mfma_f32_16x16x32_bf16(a0, b, acc[0], 0, 0, 0);
            acc[1] = __builtin_amdgcn_mfma_f32_16x16x32_bf16(a1, b, acc[1], 0, 0, 0);
        }
    }
    __syncthreads();   // ALL waves' ag reads complete before lt overwrites the tile

    // ---- transpose msgs + residual: lt[row][col] = epsv*x + msgs
#pragma unroll
    for (int m = 0; m < 2; ++m)
#pragma unroll
        for (int reg = 0; reg < 4; ++reg) {
            int row = m * 16 + kg * 4 + reg;
            int node = nbase + row;
            int nc = (node < nNodes) ? node : (nNodes - 1);
            float xv = xin[(long)nc * ND + col];
            lt[row * LPAD + col] = fmaf(epsv, xv, acc[m][reg]);
        }
    __syncthreads();

    // ---- phase 2: t = relu(h @ wm1t^T + mb1), j=wv, K=64 from lt
    f32x4 acc2[2];
    acc2[0] = (f32x4){0.f, 0.f, 0.f, 0.f};
    acc2[1] = (f32x4){0.f, 0.f, 0.f, 0.f};
#pragma unroll
    for (int m = 0; m < 2; ++m) {
        int rowl = m * 16 + r16;
#pragma unroll
        for (int kk = 0; kk < 2; ++kk) {
            int k0 = kk * 32 + kg * 8;
            float4 h0 = *(const float4*)(lt + rowl * LPAD + k0);
            float4 h1 = *(const float4*)(lt + rowl * LPAD + k0 + 4);
            us8 u;
            u[0] = bf16_rne(h0.x); u[1] = bf16_rne(h0.y);
            u[2] = bf16_rne(h0.z); u[3] = bf16_rne(h0.w);
            u[4] = bf16_rne(h1.x); u[5] = bf16_rne(h1.y);
            u[6] = bf16_rne(h1.z); u[7] = bf16_rne(h1.w);
            bf16x8 a = __builtin_bit_cast(bf16x8, u);
            bf16x8 b = *(const bf16x8*)(wm1t + (long)col * ND + k0);
            acc2[m] = __builtin_amdgcn_mfma_f32_16x16x32_bf16(a, b, acc2[m], 0, 0, 0);
        }
    }
    __syncthreads();   // phase-2 lt reads complete before overwrite

    // ---- write t (bias + relu) into lt
#pragma unroll
    for (int m = 0; m < 2; ++m)
#pragma unroll
        for (int reg = 0; reg < 4; ++reg) {
            int row = m * 16 + kg * 4 + reg;
            lt[row * LPAD + col] = fmaxf(acc2[m][reg] + mb1[col], 0.f);
        }
    __syncthreads();

    // ---- phase 3: out = t @ wm2t^T + mb2 + bias, j=wv
    f32x4 acc3[2];
    acc3[0] = (f32x4){0.f, 0.f, 0.f, 0.f};
    acc3[1] = (f32x4){0.f, 0.f, 0.f, 0.f};
#pragma unroll
    for (int m = 0; m < 2; ++m) {
        int rowl = m * 16 + r16;
#pragma unroll
        for (int kk = 0; kk < 2; ++kk) {
            int k0 = kk * 32 + kg * 8;
            float4 t0 = *(const float4*)(lt + rowl * LPAD + k0);
            float4 t1 = *(const float4*)(lt + rowl * LPAD + k0 + 4);
            us8 u;
            u[0] = bf16_rne(t0.x); u[1] = bf16_rne(t0.y);
            u[2] = bf16_rne(t0.z); u[3] = bf16_rne(t0.w);
            u[4] = bf16_rne(t1.x); u[5] = bf16_rne(t1.y);
            u[6] = bf16_rne(t1.z); u[7] = bf16_rne(t1.w);
            bf16x8 a = __builtin_bit_cast(bf16x8, u);
            bf16x8 b = *(const bf16x8*)(wm2t + (long)col * ND + k0);
            acc3[m] = __builtin_amdgcn_mfma_f32_16x16x32_bf16(a, b, acc3[m], 0, 0, 0);
        }
    }

    // ---- epilogue
    float badd = mb2[col] + bias[col];
#pragma unroll
    for (int m = 0; m < 2; ++m)
#pragma unroll
        for (int reg = 0; reg < 4; ++reg) {
            int row = nbase + m * 16 + kg * 4 + reg;
            if (row < nNodes) {
                float v = acc3[m][reg] + badd;
                out[(long)row * ND + col] = v;
                if (out_bf != nullptr)
                    out_bf[(long)row * ND + col] = bf16_rne(v);
            }
        }
}

// ---------------------------------------------------------------- launch
extern "C" void kernel_launch(void* const* d_in, const int* in_sizes, int n_in,
                              void* d_out, int out_size, void* d_ws, size_t ws_size,
                              hipStream_t stream) {
    const float* x    = (const float*)d_in[0];
    const int* esrc   = (const int*)d_in[1];
    const int* edst   = (const int*)d_in[2];
    const int* etyp   = (const int*)d_in[3];

    const float* W1   = (const float*)d_in[4];
    const float* b1   = (const float*)d_in[5];
    const float* e1   = (const float*)d_in[6];
    const float* m1w1 = (const float*)d_in[7];
    const float* m1b1 = (const float*)d_in[8];
    const float* m1w2 = (const float*)d_in[9];
    const float* m1b2 = (const float*)d_in[10];

    const float* W2   = (const float*)d_in[11];
    const float* b2   = (const float*)d_in[12];
    const float* e2   = (const float*)d_in[13];
    const float* m2w1 = (const float*)d_in[14];
    const float* m2b1 = (const float*)d_in[15];
    const float* m2w2 = (const float*)d_in[16];
    const float* m2b2 = (const float*)d_in[17];

    int nNodes = in_sizes[0] / ND;   // 50000
    int nEdges = in_sizes[1];        // 1600000
    int ntiles = (nNodes + 31) / 32; // 1563
    int Stot = ntiles * 256;

    // ---- workspace layout
    unsigned short* xhbf = (unsigned short*)d_ws;                 // N*64 bf16 (x)
    unsigned short* hbf2 = xhbf + (long)nNodes * ND;              // N*64 bf16 (h)
    unsigned short* wt1  = hbf2 + (long)nNodes * ND;
    unsigned short* wt2  = wt1 + 64 * 512;
    unsigned short* wm11 = wt2 + 64 * 512;
    unsigned short* wm12 = wm11 + 64 * 64;
    unsigned short* wm21 = wm12 + 64 * 64;
    unsigned short* wm22 = wm21 + 64 * 64;
    uint2* bbufA  = (uint2*)(wm22 + 64 * 64);                     // 13.8MB
    uint2* bbufB  = bbufA + (long)NSLICE * CAPA;                  // 19.3MB
    int* cnts     = (int*)(bbufB + (long)NTILE_AL * CAPB);
    int* bcur     = cnts;                                         // 8
    int* tilecur  = cnts + NSLICE;                                // 1568
    int* tilebase = tilecur + NTILE_AL;                           // 1568
    int* offsets  = tilebase + NTILE_AL;                          // Stot+1
    int* perm     = offsets + (Stot + 256);                       // E ints
    unsigned char* quadlist = (unsigned char*)(perm + nEdges);    // ntiles*256 B
    float* h    = (float*)d_out;   // layer-1 fp32 h aliases d_out
    float* outp = (float*)d_out;

    int n8 = nNodes * ND / 8;
    int cvtotal = 65536 + 16384 + n8;

    // ---- build per-segment CSR via LDS-staged two-level bucketing
    zeroi_kernel<<<7, 256, 0, stream>>>(cnts, NSLICE + NTILE_AL);
    bucket8_kernel<<<782, 256, 0, stream>>>(esrc, edst, etyp, bcur, bbufA, nEdges);
    subbucket_kernel<<<320, 256, 0, stream>>>(bbufA, bcur, tilecur, bbufB);
    tilescan_kernel<<<1, 256, 0, stream>>>(tilecur, tilebase, offsets, NTILE_AL, ntiles, nEdges);
    tilesort_kernel<<<ntiles, 256, 0, stream>>>(bbufB, tilecur, tilebase, offsets, perm, quadlist);

    // ---- all weight/x converts in one launch
    convert_all_kernel<<<(cvtotal + 255) / 256, 256, 0, stream>>>(
        W1, W2, m1w1, m1w2, m2w1, m2w2, (const float4*)x,
        wt1, wt2, wm11, wm12, wm21, wm22, xhbf, n8);

    // ---- layer 1 (reads xhbf, writes h + hbf2)
    fused_layer_kernel<<<ntiles, 256, 0, stream>>>(
        xhbf, offsets, perm, quadlist, x, e1, wt1, wm11, m1b1, wm12, m1b2, b1,
        h, hbf2, nNodes, nEdges - 1);

    // ---- layer 2 (reads hbf2, writes out)
    fused_layer_kernel<<<ntiles, 256, 0, stream>>>(
        hbf2, offsets, perm, quadlist, h, e2, wt2, wm21, m2b1, wm22, m2b2, b2,
        outp, nullptr, nNodes, nEdges - 1);
}